// Round 20
// baseline (173.756 us; speedup 1.0000x reference)
//
#include <hip/hip_runtime.h>
#include <hip/hip_bf16.h>
#include <cstdint>
#include <cstddef>

typedef __hip_bfloat16 bf16;
using short8 = __attribute__((ext_vector_type(8))) short;
using f32x4  = __attribute__((ext_vector_type(4))) float;

static constexpr float kTwoPi = 6.283185307179586f;

#define GLDS(g, l) __builtin_amdgcn_global_load_lds(                       \
    (const __attribute__((address_space(1))) uint32_t*)(g),                \
    (__attribute__((address_space(3))) uint32_t*)(l), 16, 0, 0)

#define BAR()   { __builtin_amdgcn_sched_barrier(0); __builtin_amdgcn_s_barrier(); \
                  asm volatile("" ::: "memory"); }
#define LGKM0() { asm volatile("s_waitcnt lgkmcnt(0)" ::: "memory"); __builtin_amdgcn_sched_barrier(0); }
#define VM6()   { asm volatile("s_waitcnt vmcnt(6)"   ::: "memory"); __builtin_amdgcn_sched_barrier(0); }
#define VM0()   { asm volatile("s_waitcnt vmcnt(0)"   ::: "memory"); __builtin_amdgcn_sched_barrier(0); }

static __device__ __forceinline__ float b2f(short u) {
    union { short s; bf16 h; } c; c.s = u; return __bfloat162float(c.h);
}

// -------------------- prep: W -> Wr [1024][512] + br + Wcp (Nyquist cols, f32)
__global__ void prep_w_k(const float* __restrict__ W, const float* __restrict__ b,
                         bf16* __restrict__ Wr, float* __restrict__ br,
                         float* __restrict__ Wcp) {
    int j = blockIdx.x;
    if (j < 1024) {
        int col = (j & 1) ? 513 + (j >> 1) : (j >> 1);
        for (int k = threadIdx.x; k < 512; k += 256)
            Wr[(size_t)j * 512 + k] = __float2bfloat16(W[(size_t)k * 1026 + col]);
        if (threadIdx.x == 0) br[j] = b[col];
    } else {
        int col = (j == 1024) ? 512 : 1025;
        for (int k = threadIdx.x; k < 512; k += 256)
            Wcp[(j - 1024) * 512 + k] = W[(size_t)k * 1026 + col];
        if (threadIdx.x == 0) Wcp[1024 + (j - 1024)] = b[col];
    }
}

// ------------------- prep: x -> bf16, fused Nyquist-bin dot (f32) -> R512[row]
__global__ void cvt_x_k(const float* __restrict__ x, bf16* __restrict__ xb,
                        const float* __restrict__ Wcp, float* __restrict__ R512) {
    const int tid = threadIdx.x, w = tid >> 6, lane = tid & 63;
    size_t i = ((size_t)blockIdx.x * 256 + tid) * 8;
    float4 a = *(const float4*)(x + i);
    float4 c = *(const float4*)(x + i + 4);
    union { bf16 h[8]; uint4 u; } o;
    o.h[0] = __float2bfloat16(a.x); o.h[1] = __float2bfloat16(a.y);
    o.h[2] = __float2bfloat16(a.z); o.h[3] = __float2bfloat16(a.w);
    o.h[4] = __float2bfloat16(c.x); o.h[5] = __float2bfloat16(c.y);
    o.h[6] = __float2bfloat16(c.z); o.h[7] = __float2bfloat16(c.w);
    *(uint4*)(xb + i) = o.u;
    const int kb = lane * 8;
    float4 m0 = *(const float4*)(Wcp + kb);
    float4 m1 = *(const float4*)(Wcp + kb + 4);
    float4 p0 = *(const float4*)(Wcp + 512 + kb);
    float4 p1 = *(const float4*)(Wcp + 512 + kb + 4);
    float dm = a.x*m0.x + a.y*m0.y + a.z*m0.z + a.w*m0.w
             + c.x*m1.x + c.y*m1.y + c.z*m1.z + c.w*m1.w;
    float dp = a.x*p0.x + a.y*p0.y + a.z*p0.z + a.w*p0.w
             + c.x*p1.x + c.y*p1.y + c.z*p1.z + c.w*p1.w;
    #pragma unroll
    for (int off = 32; off; off >>= 1) {
        dm += __shfl_xor(dm, off);
        dp += __shfl_xor(dp, off);
    }
    if (lane == 0) {
        float mag = fminf(__expf(dm + Wcp[1024]), 100.0f);
        R512[blockIdx.x * 4 + w] = mag * __cosf(dp + Wcp[1025]);
    }
}

// ------------------------- prep: Mc/Ms [512][512] cos/sin irfft half-matrices
__global__ void prep_mcs_k(bf16* __restrict__ Mc, bf16* __restrict__ Ms) {
    const int r = blockIdx.x;                     // output row n-bar (0..511)
    for (int kk = threadIdx.x; kk < 512; kk += 256) {
        int mm = (kk * r) & 1023;
        float ang = kTwoPi * (float)mm * (1.0f / 1024.0f);
        float alpha = (kk == 0) ? 1.0f : 2.0f;
        Mc[(size_t)r * 512 + kk] = __float2bfloat16(alpha * (1.0f / 1024.0f) * cosf(ang));
        Ms[(size_t)r * 512 + kk] = __float2bfloat16(alpha * (1.0f / 1024.0f) * sinf(ang));
    }
}

// ------------------------------------------------------- prep: window tables
__global__ void prep_win_k(float* __restrict__ wg) {
    const int idx = blockIdx.x * 256 + threadIdx.x;   // 0..1023
    float wn = 0.5f - 0.5f * cosf(kTwoPi * (float)idx / 1023.0f);  // numpy hanning
    wg[idx] = wn;
    wg[1024 + idx] = wn * wn;
}

// --------------------- GEMM1: 256x128, BK=32, 4 waves (2M x 2N), wave tile 128x64.
// LDS reads/block-iter 64KB -> 48KB vs 8-wave grid (B redundancy 4x -> 2x) — R19
// counters showed LDS-read-throughput bound (MfmaUtil 22% == 320/1540 cyc model).
// 3 slabs x 24KB = 72KB -> 2 blocks/CU. Swizzle: slot ^ (row&3)^((row>>2)&3).
// Epilogue: Vocos + tile-local [Re_64 | Im_64] de-interleave.
__global__ __launch_bounds__(256, 2)
void gemm1_k(const bf16* __restrict__ A, const bf16* __restrict__ B,
             const float* __restrict__ bias, bf16* __restrict__ O)
{
    extern __shared__ __align__(16) bf16 lds[];   // 3 slabs x 12288 elems
    const int tid  = threadIdx.x;
    const int w    = tid >> 6;                    // 0..3
    const int lane = tid & 63;
    const int wr = w >> 1, wc = w & 1;            // wave grid 2(M) x 2(N)

    const int nwg = gridDim.x, orig = blockIdx.x;
    const int bid = (orig & 7) * (nwg >> 3) + (orig >> 3);
    const int nt = bid & 7, mt = bid >> 3;
    const int row0 = mt * 256;
    const int col0 = nt * 128;

    const int q = lane >> 2;
    const int gslot = (lane & 3) ^ ((lane >> 2) & 3) ^ ((lane >> 4) & 3);

    const bf16* gA0 = A + (size_t)(row0 + q) * 512 + gslot * 8;
    const bf16* gB0 = B + (size_t)(col0 + q) * 512 + gslot * 8;

    auto stage = [&](int t, int s) {
        bf16* lA = lds + s * 12288;
        bf16* lB = lA + 8192;
        #pragma unroll
        for (int l = 0; l < 4; ++l) {
            const int c = w * 4 + l;              // A: 16 chunks of 16 rows
            GLDS(gA0 + (size_t)(16 * c) * 512 + (size_t)t * 32, lA + c * 512 + lane * 8);
        }
        #pragma unroll
        for (int l = 0; l < 2; ++l) {
            const int d = w * 2 + l;              // B: 8 chunks of 16 rows
            GLDS(gB0 + (size_t)(16 * d) * 512 + (size_t)t * 32, lB + d * 512 + lane * 8);
        }
    };

    short8 af[8], bq[4];
    auto ldregs = [&](int s) {
        const bf16* lA = lds + s * 12288;
        const bf16* lB = lA + 8192;
        const int sl = (lane >> 4) ^ (lane & 3) ^ ((lane >> 2) & 3);  // s ^ m(r)
        #pragma unroll
        for (int fm = 0; fm < 8; ++fm) {
            const int r = wr * 128 + fm * 16 + (lane & 15);
            af[fm] = *(const short8*)(lA + r * 32 + sl * 8);
        }
        #pragma unroll
        for (int fn = 0; fn < 4; ++fn) {
            const int r = wc * 64 + fn * 16 + (lane & 15);
            bq[fn] = *(const short8*)(lB + r * 32 + sl * 8);
        }
    };

    f32x4 acc[8][4] = {};

    stage(0, 0);
    stage(1, 1);
    VM6();
    BAR();

    for (int t = 0; t < 16; ++t) {
        const int tp = (t + 2 < 16) ? t + 2 : 15;
        ldregs(t % 3);
        stage(tp, (t + 2) % 3);
        VM6();                                    // retire stage(t+1)
        LGKM0();
        BAR();
        __builtin_amdgcn_s_setprio(1);
        #pragma unroll
        for (int fm = 0; fm < 8; ++fm)
            #pragma unroll
            for (int fn = 0; fn < 4; ++fn)
                acc[fm][fn] = __builtin_amdgcn_mfma_f32_16x16x32_bf16(
                    af[fm], bq[fn], acc[fm][fn], 0, 0, 0);
        __builtin_amdgcn_s_setprio(0);
    }
    VM0();
    BAR();                                        // LDS free for epilogue

    // epilogue: acc -> LDS (swizzled, tile-local deinterleave) -> coalesced store
    char* eb = (char*)lds;                        // [256 rows][256 B] = 64KB
    #pragma unroll
    for (int fm = 0; fm < 8; ++fm) {
        #pragma unroll
        for (int fn = 0; fn < 4; ++fn) {
            const int col = wc * 64 + fn * 16 + (lane & 15);     // 0..127 in tile
            const int n   = col0 + col;                          // < 1024 always
            #pragma unroll
            for (int r = 0; r < 4; ++r) {
                const int row = wr * 128 + fm * 16 + (lane >> 4) * 4 + r;
                float v = acc[fm][fn][r] + bias[n];
                float vo = __shfl_xor(v, 1);
                float res = (n & 1) ? fminf(__expf(vo), 100.0f) * __sinf(v)
                                    : fminf(__expf(v), 100.0f) * __cosf(vo);
                const int colp = (col >> 1) + ((col & 1) << 6);  // [Re_64 | Im_64]
                const int sw = (colp >> 3) ^ (((row >> 2) & 7) << 1);
                *(bf16*)(eb + row * 256 + sw * 16 + (colp & 7) * 2) =
                    __float2bfloat16(res);
            }
        }
    }
    asm volatile("s_waitcnt lgkmcnt(0)" ::: "memory");
    BAR();

    #pragma unroll
    for (int k2 = 0; k2 < 16; ++k2) {
        const int g   = tid + k2 * 256;           // 0..4095 16B-chunks
        const int row = g >> 4;
        const int s   = g & 15;
        const int sw  = s ^ (((row >> 2) & 7) << 1);
        short8 vv = *(const short8*)(eb + row * 256 + sw * 16);
        const int colg = col0 + s * 8;
        *(short8*)(O + (size_t)(row0 + row) * 1032 + colg) = vv;
    }
}

// ----------- e512_k: E512[row] = sum_k alpha_k (-1)^k Re_k / 1024 (f32, exact coefs)
__global__ void e512_k(const bf16* __restrict__ S, float* __restrict__ E512) {
    const int tid = threadIdx.x, w = tid >> 6, lane = tid & 63;
    const int row = blockIdx.x * 4 + w;
    const bf16* rp = S + (size_t)row * 1032;
    float acc = 0.0f;
    #pragma unroll
    for (int j = 0; j < 8; ++j) {
        float v = __bfloat162float(rp[j * 128 + lane]);
        float coef = (j == 0 && lane == 0) ? 1.0f : ((lane & 1) ? -2.0f : 2.0f);
        acc += v * coef;
    }
    #pragma unroll
    for (int off = 32; off; off >>= 1) acc += __shfl_xor(acc, off);
    if (lane == 0) E512[row] = acc * (1.0f / 1024.0f);
}

// ---------------- GEMM2: accE = Re@Mc^T (t=0..7), accO = Im@Ms^T (t=8..15), split
// loops, BK=64, 144KB LDS. Grid 512 = 128mt x 4nt = exactly 2.0 rounds.
__global__ __launch_bounds__(512, 1)
void gemm2_k(const bf16* __restrict__ S, const bf16* __restrict__ Mc,
             const bf16* __restrict__ Ms, bf16* __restrict__ pe,
             bf16* __restrict__ po)
{
    extern __shared__ __align__(16) bf16 lds[];
    const int tid  = threadIdx.x;
    const int w    = tid >> 6;
    const int lane = tid & 63;
    const int wr = w >> 1, wc = w & 1;

    const int nwg = gridDim.x, orig = blockIdx.x;
    const int bid = (orig & 7) * (nwg >> 3) + (orig >> 3);
    const int nt = bid & 3, mt = bid >> 2;
    const int row0 = mt * 256;
    const int col0 = nt * 128;

    const int srow  = lane >> 3;
    const int sslot = (lane & 7) ^ srow;

    const bf16* gA0 = S  + (size_t)(row0 + srow) * 1032 + sslot * 8;
    const bf16* gBc = Mc + (size_t)(col0 + srow) * 512 + sslot * 8;
    const bf16* gBs = Ms + (size_t)(col0 + srow) * 512 + sslot * 8;

    auto stage = [&](int t, int s) {
        bf16* lA = lds + s * 24576;
        bf16* lB = lA + 16384;
        const bf16* gB = (t < 8) ? gBc : gBs;
        const size_t aoff = (t < 8) ? (size_t)t * 128 : (size_t)(t - 8) * 128 + 64;
        const int tk = t & 7;
        #pragma unroll
        for (int l = 0; l < 4; ++l) {
            const int c = w * 4 + l;
            GLDS(gA0 + (size_t)(8 * c) * 1032 + aoff, lA + c * 512 + lane * 8);
        }
        #pragma unroll
        for (int l = 0; l < 2; ++l) {
            const int d = w * 2 + l;
            GLDS(gB + (size_t)(8 * d) * 512 + (size_t)tk * 64, lB + d * 512 + lane * 8);
        }
    };

    short8 af[4][2], bq[4][2];
    auto ldregs = [&](int s) {
        const bf16* lA = lds + s * 24576;
        const bf16* lB = lA + 16384;
        #pragma unroll
        for (int fm = 0; fm < 4; ++fm)
            #pragma unroll
            for (int ks = 0; ks < 2; ++ks) {
                const int r  = wr * 64 + fm * 16 + (lane & 15);
                const int sl = (ks * 4 + (lane >> 4)) ^ (r & 7);
                af[fm][ks] = *(const short8*)(lA + r * 64 + sl * 8);
            }
        #pragma unroll
        for (int fn = 0; fn < 4; ++fn)
            #pragma unroll
            for (int ks = 0; ks < 2; ++ks) {
                const int r  = wc * 64 + fn * 16 + (lane & 15);
                const int sl = (ks * 4 + (lane >> 4)) ^ (r & 7);
                bq[fn][ks] = *(const short8*)(lB + r * 64 + sl * 8);
            }
    };

    f32x4 accE[4][4] = {}, accO[4][4] = {};

    #define MMA2(ACC) {                                                        \
        __builtin_amdgcn_s_setprio(1);                                         \
        _Pragma("unroll") for (int ks = 0; ks < 2; ++ks)                       \
          _Pragma("unroll") for (int fm = 0; fm < 4; ++fm)                     \
            _Pragma("unroll") for (int fn = 0; fn < 4; ++fn)                   \
              ACC[fm][fn] = __builtin_amdgcn_mfma_f32_16x16x32_bf16(           \
                  af[fm][ks], bq[fn][ks], ACC[fm][fn], 0, 0, 0);               \
        __builtin_amdgcn_s_setprio(0); }

    stage(0, 0);
    stage(1, 1);
    VM6();
    BAR();

    for (int t = 0; t < 8; ++t) {                 // first half: accE (Re @ Mc^T)
        ldregs(t % 3);
        stage(t + 2, (t + 2) % 3);                // t+2 <= 9 < 16, always real
        VM6();
        LGKM0();
        BAR();
        MMA2(accE);
    }
    for (int t = 8; t < 16; ++t) {                // second half: accO (Im @ Ms^T)
        const int tp = (t + 2 < 16) ? t + 2 : 15;
        ldregs(t % 3);
        stage(tp, (t + 2) % 3);
        VM6();
        LGKM0();
        BAR();
        MMA2(accO);
    }
    VM0();
    BAR();
    #undef MMA2

    // two-pass epilogue: accE -> pe tile, accO -> po tile (stride 512)
    char* eb = (char*)lds;
    #define EPIPASS(ACC, DST) {                                                 \
        _Pragma("unroll") for (int fm = 0; fm < 4; ++fm)                        \
        _Pragma("unroll") for (int fn = 0; fn < 4; ++fn) {                      \
            const int col = wc * 64 + fn * 16 + (lane & 15);                    \
            _Pragma("unroll") for (int r = 0; r < 4; ++r) {                     \
                const int row = wr * 64 + fm * 16 + (lane >> 4) * 4 + r;        \
                const int sw = (col >> 3) ^ (((row >> 2) & 7) << 1);            \
                *(bf16*)(eb + row * 256 + sw * 16 + (col & 7) * 2) =            \
                    __float2bfloat16(ACC[fm][fn][r]);                           \
            }                                                                   \
        }                                                                       \
        asm volatile("s_waitcnt lgkmcnt(0)" ::: "memory");                      \
        BAR();                                                                  \
        _Pragma("unroll") for (int k2 = 0; k2 < 8; ++k2) {                      \
            const int g   = tid + k2 * 512;                                     \
            const int row = g >> 4;                                             \
            const int s   = g & 15;                                             \
            const int sw  = s ^ (((row >> 2) & 7) << 1);                        \
            short8 vv = *(const short8*)(eb + row * 256 + sw * 16);             \
            const int colg = col0 + s * 8;                                      \
            *(short8*)(DST + (size_t)(row0 + row) * 512 + colg) = vv;           \
        }                                                                       \
        BAR();                                                                  \
    }
    EPIPASS(accE, pe)
    EPIPASS(accO, po)
    #undef EPIPASS
}

// ------- overlap-add: frames[n] = (e[nbar] + (-1)^n R512/1024 -+ o[nbar]) * w[n]
__global__ void ola_k(const bf16* __restrict__ pe, const bf16* __restrict__ po,
                      const float* __restrict__ R512, const float* __restrict__ E512,
                      const float* __restrict__ wg, float* __restrict__ out) {
    __shared__ float w[1024], w2[1024];
    for (int i = threadIdx.x; i < 1024; i += 256) { w[i] = wg[i]; w2[i] = wg[1024 + i]; }
    __syncthreads();
    const int gid = blockIdx.x * 256 + threadIdx.x;
    const int o0  = gid * 8;
    const int bb  = o0 >> 19;
    const int oo  = o0 & 524287;
    const int s   = oo + 384;                     // multiple of 8
    const int tmax = s >> 8;
    float sum[8] = {}, env[8] = {};
    #pragma unroll
    for (int jj = 0; jj < 4; ++jj) {
        const int t = tmax - jj;
        if (t < 0 || t >= 2048) continue;
        const int n0 = s - (t << 8);              // [0,1016], multiple of 8
        const size_t rowi = (size_t)bb * 2048 + t;
        const size_t rb = rowi * 512;
        const float rc = R512[rowi] * (1.0f / 1024.0f);
        if (n0 <= 504) {                          // n = n0+e, parity = e&1
            short8 E  = *(const short8*)(pe + rb + n0);
            short8 Og = *(const short8*)(po + rb + n0);
            #pragma unroll
            for (int e = 0; e < 8; ++e) {
                float ev = b2f(E[e]) + ((e & 1) ? -rc : rc);
                sum[e] += (ev - b2f(Og[e])) * w[n0 + e];
                env[e] += w2[n0 + e];
            }
        } else {
            const int nb = 1024 - n0;             // [8,512], multiple of 8
            short8 Ea = *(const short8*)(pe + rb + nb - 8);
            short8 Oa = *(const short8*)(po + rb + nb - 8);
            float e0, o0v;
            if (nb < 512) {
                e0  = b2f(*(const short*)(pe + rb + nb));
                o0v = b2f(*(const short*)(po + rb + nb));
            } else {                              // nbar == 512
                e0  = E512[rowi];
                o0v = 0.0f;
            }
            sum[0] += (e0 + rc + o0v) * w[n0];
            env[0] += w2[n0];
            #pragma unroll
            for (int j = 1; j < 8; ++j) {
                float ev = b2f(Ea[8 - j]) + ((j & 1) ? -rc : rc);
                sum[j] += (ev + b2f(Oa[8 - j])) * w[n0 + j];
                env[j] += w2[n0 + j];
            }
        }
    }
    float4 r0, r1;
    r0.x = sum[0] / (env[0] + 1e-11f); r0.y = sum[1] / (env[1] + 1e-11f);
    r0.z = sum[2] / (env[2] + 1e-11f); r0.w = sum[3] / (env[3] + 1e-11f);
    r1.x = sum[4] / (env[4] + 1e-11f); r1.y = sum[5] / (env[5] + 1e-11f);
    r1.z = sum[6] / (env[6] + 1e-11f); r1.w = sum[7] / (env[7] + 1e-11f);
    *(float4*)(out + o0)     = r0;
    *(float4*)(out + o0 + 4) = r1;
}

// ---------------------------------------------------------------------- launcher
// ws budget ~137.5 MB, below the proven 140.6 MB bound.
extern "C" void kernel_launch(void* const* d_in, const int* in_sizes, int n_in,
                              void* d_out, int out_size, void* d_ws, size_t ws_size,
                              hipStream_t stream)
{
    const float* x = (const float*)d_in[0];
    const float* W = (const float*)d_in[1];
    const float* b = (const float*)d_in[2];
    float* out = (float*)d_out;

    char* ws = (char*)d_ws;
    size_t off = 0;
    auto alloc = [&](size_t bytes) { char* p = ws + off; off += (bytes + 255) & ~255ull; return p; };

    bf16*  Mc   = (bf16*) alloc(512ull * 512 * 2);     //    524,288
    bf16*  Ms   = (bf16*) alloc(512ull * 512 * 2);     //    524,288
    float* wg   = (float*)alloc(2048 * 4);             //      8,192
    float* br   = (float*)alloc(1152 * 4);             //      4,608
    float* Wcp  = (float*)alloc(1026 * 4);             //      4,104
    float* R512 = (float*)alloc(32768ull * 4);         //    131,072
    float* E512 = (float*)alloc(32768ull * 4);         //    131,072
    bf16*  Sri  = (bf16*) alloc(32768ull * 1032 * 2);  // 67,633,152
    char*  regC = alloc(68157440ull);                  // 68,157,440 (aliased)
    bf16*  xb = (bf16*)regC;                           // phase 1 (GEMM1 input)
    bf16*  Wr = (bf16*)(regC + 33554432ull);           // phase 1 [1024][512]
    bf16*  pe = (bf16*)regC;                           // phase 2 e [32768][512]
    bf16*  po = (bf16*)(regC + 33554432ull);           // phase 2 o [32768][512]

    hipFuncSetAttribute(reinterpret_cast<const void*>(gemm1_k),
                        hipFuncAttributeMaxDynamicSharedMemorySize, 73728);
    hipFuncSetAttribute(reinterpret_cast<const void*>(gemm2_k),
                        hipFuncAttributeMaxDynamicSharedMemorySize, 147456);

    prep_w_k  <<<dim3(1026),  dim3(256), 0, stream>>>(W, b, Wr, br, Wcp);
    cvt_x_k   <<<dim3(8192),  dim3(256), 0, stream>>>(x, xb, Wcp, R512);
    prep_mcs_k<<<dim3(512),   dim3(256), 0, stream>>>(Mc, Ms);
    prep_win_k<<<dim3(4),     dim3(256), 0, stream>>>(wg);
    // GEMM1: Sri = epi(xb @ Wr^T), 128x64 wave tiles, BK=32, 2 blocks/CU
    gemm1_k<<<dim3(1024), dim3(256), 73728, stream>>>(xb, Wr, br, Sri);
    // e[512] per row (alternating Re sum, f32)
    e512_k <<<dim3(8192), dim3(256), 0, stream>>>(Sri, E512);
    // GEMM2: accE/accO split-loop BK=64 pipeline, grid 512 = 2.0 rounds -> pe, po
    gemm2_k<<<dim3(512), dim3(512), 147456, stream>>>(Sri, Mc, Ms, pe, po);
    // OLA + fold combine + envelope normalize + trim
    ola_k  <<<dim3(4096), dim3(256), 0, stream>>>(pe, po, R512, E512, wg, out);
    (void)in_sizes; (void)n_in; (void)out_size; (void)ws_size;
}

// Round 21
// 165.599 us; speedup vs baseline: 1.0493x; 1.0493x over previous
//
#include <hip/hip_runtime.h>
#include <hip/hip_bf16.h>
#include <cstdint>
#include <cstddef>

typedef __hip_bfloat16 bf16;
using short8 = __attribute__((ext_vector_type(8))) short;
using f32x4  = __attribute__((ext_vector_type(4))) float;

static constexpr float kTwoPi = 6.283185307179586f;

#define GLDS(g, l) __builtin_amdgcn_global_load_lds(                       \
    (const __attribute__((address_space(1))) uint32_t*)(g),                \
    (__attribute__((address_space(3))) uint32_t*)(l), 16, 0, 0)

#define BAR()   { __builtin_amdgcn_sched_barrier(0); __builtin_amdgcn_s_barrier(); \
                  asm volatile("" ::: "memory"); }
#define LGKM0() { asm volatile("s_waitcnt lgkmcnt(0)" ::: "memory"); __builtin_amdgcn_sched_barrier(0); }
#define VM6()   { asm volatile("s_waitcnt vmcnt(6)"   ::: "memory"); __builtin_amdgcn_sched_barrier(0); }
#define VM3()   { asm volatile("s_waitcnt vmcnt(3)"   ::: "memory"); __builtin_amdgcn_sched_barrier(0); }
#define VM0()   { asm volatile("s_waitcnt vmcnt(0)"   ::: "memory"); __builtin_amdgcn_sched_barrier(0); }

static __device__ __forceinline__ float b2f(short u) {
    union { short s; bf16 h; } c; c.s = u; return __bfloat162float(c.h);
}

// -------------------- prep: W -> Wr [1024][512] + br + Wcp (Nyquist cols, f32)
__global__ void prep_w_k(const float* __restrict__ W, const float* __restrict__ b,
                         bf16* __restrict__ Wr, float* __restrict__ br,
                         float* __restrict__ Wcp) {
    int j = blockIdx.x;
    if (j < 1024) {
        int col = (j & 1) ? 513 + (j >> 1) : (j >> 1);
        for (int k = threadIdx.x; k < 512; k += 256)
            Wr[(size_t)j * 512 + k] = __float2bfloat16(W[(size_t)k * 1026 + col]);
        if (threadIdx.x == 0) br[j] = b[col];
    } else {
        int col = (j == 1024) ? 512 : 1025;
        for (int k = threadIdx.x; k < 512; k += 256)
            Wcp[(j - 1024) * 512 + k] = W[(size_t)k * 1026 + col];
        if (threadIdx.x == 0) Wcp[1024 + (j - 1024)] = b[col];
    }
}

// ------------------- prep: x -> bf16, fused Nyquist-bin dot (f32) -> R512[row]
__global__ void cvt_x_k(const float* __restrict__ x, bf16* __restrict__ xb,
                        const float* __restrict__ Wcp, float* __restrict__ R512) {
    const int tid = threadIdx.x, w = tid >> 6, lane = tid & 63;
    size_t i = ((size_t)blockIdx.x * 256 + tid) * 8;
    float4 a = *(const float4*)(x + i);
    float4 c = *(const float4*)(x + i + 4);
    union { bf16 h[8]; uint4 u; } o;
    o.h[0] = __float2bfloat16(a.x); o.h[1] = __float2bfloat16(a.y);
    o.h[2] = __float2bfloat16(a.z); o.h[3] = __float2bfloat16(a.w);
    o.h[4] = __float2bfloat16(c.x); o.h[5] = __float2bfloat16(c.y);
    o.h[6] = __float2bfloat16(c.z); o.h[7] = __float2bfloat16(c.w);
    *(uint4*)(xb + i) = o.u;
    const int kb = lane * 8;
    float4 m0 = *(const float4*)(Wcp + kb);
    float4 m1 = *(const float4*)(Wcp + kb + 4);
    float4 p0 = *(const float4*)(Wcp + 512 + kb);
    float4 p1 = *(const float4*)(Wcp + 512 + kb + 4);
    float dm = a.x*m0.x + a.y*m0.y + a.z*m0.z + a.w*m0.w
             + c.x*m1.x + c.y*m1.y + c.z*m1.z + c.w*m1.w;
    float dp = a.x*p0.x + a.y*p0.y + a.z*p0.z + a.w*p0.w
             + c.x*p1.x + c.y*p1.y + c.z*p1.z + c.w*p1.w;
    #pragma unroll
    for (int off = 32; off; off >>= 1) {
        dm += __shfl_xor(dm, off);
        dp += __shfl_xor(dp, off);
    }
    if (lane == 0) {
        float mag = fminf(__expf(dm + Wcp[1024]), 100.0f);
        R512[blockIdx.x * 4 + w] = mag * __cosf(dp + Wcp[1025]);
    }
}

// ------------------------- prep: Mc/Ms [512][512] cos/sin irfft half-matrices
__global__ void prep_mcs_k(bf16* __restrict__ Mc, bf16* __restrict__ Ms) {
    const int r = blockIdx.x;                     // output row n-bar (0..511)
    for (int kk = threadIdx.x; kk < 512; kk += 256) {
        int mm = (kk * r) & 1023;
        float ang = kTwoPi * (float)mm * (1.0f / 1024.0f);
        float alpha = (kk == 0) ? 1.0f : 2.0f;
        Mc[(size_t)r * 512 + kk] = __float2bfloat16(alpha * (1.0f / 1024.0f) * cosf(ang));
        Ms[(size_t)r * 512 + kk] = __float2bfloat16(alpha * (1.0f / 1024.0f) * sinf(ang));
    }
}

// ------------------------------------------------------- prep: window tables
__global__ void prep_win_k(float* __restrict__ wg) {
    const int idx = blockIdx.x * 256 + threadIdx.x;   // 0..1023
    float wn = 0.5f - 0.5f * cosf(kTwoPi * (float)idx / 1023.0f);  // numpy hanning
    wg[idx] = wn;
    wg[1024 + idx] = wn * wn;
}

// --------------------- GEMM1 (R19 body, measured 59.4us — best): 256x128, BK=32,
// 8 waves 4Mx2N, 3 slabs x 24KB = 72KB -> 2 blocks/CU (16 waves/CU latency hiding;
// R20's 4-wave fat-tile variant measured WORSE, 67us). Swizzle: slot^(row&3)^((row>>2)&3).
// Epilogue: Vocos + tile-local [Re_64 | Im_64] de-interleave.
__global__ __launch_bounds__(512, 4)
void gemm1_k(const bf16* __restrict__ A, const bf16* __restrict__ B,
             const float* __restrict__ bias, bf16* __restrict__ O)
{
    extern __shared__ __align__(16) bf16 lds[];   // 3 slabs x 12288 elems
    const int tid  = threadIdx.x;
    const int w    = tid >> 6;
    const int lane = tid & 63;
    const int wr = w >> 1, wc = w & 1;            // wave grid 4(M) x 2(N)

    const int nwg = gridDim.x, orig = blockIdx.x;
    const int bid = (orig & 7) * (nwg >> 3) + (orig >> 3);
    const int nt = bid & 7, mt = bid >> 3;
    const int row0 = mt * 256;
    const int col0 = nt * 128;

    const int q = lane >> 2;
    const int gslot = (lane & 3) ^ ((lane >> 2) & 3) ^ ((lane >> 4) & 3);

    const bf16* gA0 = A + (size_t)(row0 + q) * 512 + gslot * 8;
    const bf16* gB0 = B + (size_t)(col0 + q) * 512 + gslot * 8;

    auto stage = [&](int t, int s) {
        bf16* lA = lds + s * 12288;
        bf16* lB = lA + 8192;
        #pragma unroll
        for (int l = 0; l < 2; ++l) {
            const int c = w * 2 + l;              // A: 16 chunks of 16 rows
            GLDS(gA0 + (size_t)(16 * c) * 512 + (size_t)t * 32, lA + c * 512 + lane * 8);
        }
        GLDS(gB0 + (size_t)(16 * w) * 512 + (size_t)t * 32, lB + w * 512 + lane * 8);
    };

    short8 af[4], bq[4];
    auto ldregs = [&](int s) {
        const bf16* lA = lds + s * 12288;
        const bf16* lB = lA + 8192;
        const int sl = (lane >> 4) ^ (lane & 3) ^ ((lane >> 2) & 3);  // s ^ m(r)
        #pragma unroll
        for (int fm = 0; fm < 4; ++fm) {
            const int r = wr * 64 + fm * 16 + (lane & 15);
            af[fm] = *(const short8*)(lA + r * 32 + sl * 8);
        }
        #pragma unroll
        for (int fn = 0; fn < 4; ++fn) {
            const int r = wc * 64 + fn * 16 + (lane & 15);
            bq[fn] = *(const short8*)(lB + r * 32 + sl * 8);
        }
    };

    f32x4 acc[4][4] = {};

    stage(0, 0);
    stage(1, 1);
    VM3();
    BAR();

    for (int t = 0; t < 16; ++t) {
        const int tp = (t + 2 < 16) ? t + 2 : 15;
        ldregs(t % 3);
        stage(tp, (t + 2) % 3);
        VM3();                                    // retire stage(t+1)
        LGKM0();
        BAR();
        __builtin_amdgcn_s_setprio(1);
        #pragma unroll
        for (int fm = 0; fm < 4; ++fm)
            #pragma unroll
            for (int fn = 0; fn < 4; ++fn)
                acc[fm][fn] = __builtin_amdgcn_mfma_f32_16x16x32_bf16(
                    af[fm], bq[fn], acc[fm][fn], 0, 0, 0);
        __builtin_amdgcn_s_setprio(0);
    }
    VM0();
    BAR();                                        // LDS free for epilogue

    // epilogue: acc -> LDS (swizzled, tile-local deinterleave) -> coalesced store
    char* eb = (char*)lds;                        // [256 rows][256 B] = 64KB
    #pragma unroll
    for (int fm = 0; fm < 4; ++fm) {
        #pragma unroll
        for (int fn = 0; fn < 4; ++fn) {
            const int col = wc * 64 + fn * 16 + (lane & 15);     // 0..127 in tile
            const int n   = col0 + col;                          // < 1024 always
            #pragma unroll
            for (int r = 0; r < 4; ++r) {
                const int row = wr * 64 + fm * 16 + (lane >> 4) * 4 + r;
                float v = acc[fm][fn][r] + bias[n];
                float vo = __shfl_xor(v, 1);
                float res = (n & 1) ? fminf(__expf(vo), 100.0f) * __sinf(v)
                                    : fminf(__expf(v), 100.0f) * __cosf(vo);
                const int colp = (col >> 1) + ((col & 1) << 6);  // [Re_64 | Im_64]
                const int sw = (colp >> 3) ^ (((row >> 2) & 7) << 1);
                *(bf16*)(eb + row * 256 + sw * 16 + (colp & 7) * 2) =
                    __float2bfloat16(res);
            }
        }
    }
    asm volatile("s_waitcnt lgkmcnt(0)" ::: "memory");
    BAR();

    #pragma unroll
    for (int k2 = 0; k2 < 8; ++k2) {
        const int g   = tid + k2 * 512;           // 0..4095 16B-chunks
        const int row = g >> 4;
        const int s   = g & 15;
        const int sw  = s ^ (((row >> 2) & 7) << 1);
        short8 vv = *(const short8*)(eb + row * 256 + sw * 16);
        const int colg = col0 + s * 8;
        *(short8*)(O + (size_t)(row0 + row) * 1032 + colg) = vv;
    }
}

// ----------- e512_k: E512[row] = sum_k alpha_k (-1)^k Re_k / 1024 (f32, exact coefs)
__global__ void e512_k(const bf16* __restrict__ S, float* __restrict__ E512) {
    const int tid = threadIdx.x, w = tid >> 6, lane = tid & 63;
    const int row = blockIdx.x * 4 + w;
    const bf16* rp = S + (size_t)row * 1032;
    float acc = 0.0f;
    #pragma unroll
    for (int j = 0; j < 8; ++j) {
        float v = __bfloat162float(rp[j * 128 + lane]);
        float coef = (j == 0 && lane == 0) ? 1.0f : ((lane & 1) ? -2.0f : 2.0f);
        acc += v * coef;
    }
    #pragma unroll
    for (int off = 32; off; off >>= 1) acc += __shfl_xor(acc, off);
    if (lane == 0) E512[row] = acc * (1.0f / 1024.0f);
}

// ---------------- GEMM2: accE = Re@Mc^T (t=0..7), accO = Im@Ms^T (t=8..15), split
// loops, BK=64, 144KB LDS. Grid 512 = 128mt x 4nt = exactly 2.0 rounds.
__global__ __launch_bounds__(512, 1)
void gemm2_k(const bf16* __restrict__ S, const bf16* __restrict__ Mc,
             const bf16* __restrict__ Ms, bf16* __restrict__ pe,
             bf16* __restrict__ po)
{
    extern __shared__ __align__(16) bf16 lds[];
    const int tid  = threadIdx.x;
    const int w    = tid >> 6;
    const int lane = tid & 63;
    const int wr = w >> 1, wc = w & 1;

    const int nwg = gridDim.x, orig = blockIdx.x;
    const int bid = (orig & 7) * (nwg >> 3) + (orig >> 3);
    const int nt = bid & 3, mt = bid >> 2;
    const int row0 = mt * 256;
    const int col0 = nt * 128;

    const int srow  = lane >> 3;
    const int sslot = (lane & 7) ^ srow;

    const bf16* gA0 = S  + (size_t)(row0 + srow) * 1032 + sslot * 8;
    const bf16* gBc = Mc + (size_t)(col0 + srow) * 512 + sslot * 8;
    const bf16* gBs = Ms + (size_t)(col0 + srow) * 512 + sslot * 8;

    auto stage = [&](int t, int s) {
        bf16* lA = lds + s * 24576;
        bf16* lB = lA + 16384;
        const bf16* gB = (t < 8) ? gBc : gBs;
        const size_t aoff = (t < 8) ? (size_t)t * 128 : (size_t)(t - 8) * 128 + 64;
        const int tk = t & 7;
        #pragma unroll
        for (int l = 0; l < 4; ++l) {
            const int c = w * 4 + l;
            GLDS(gA0 + (size_t)(8 * c) * 1032 + aoff, lA + c * 512 + lane * 8);
        }
        #pragma unroll
        for (int l = 0; l < 2; ++l) {
            const int d = w * 2 + l;
            GLDS(gB + (size_t)(8 * d) * 512 + (size_t)tk * 64, lB + d * 512 + lane * 8);
        }
    };

    short8 af[4][2], bq[4][2];
    auto ldregs = [&](int s) {
        const bf16* lA = lds + s * 24576;
        const bf16* lB = lA + 16384;
        #pragma unroll
        for (int fm = 0; fm < 4; ++fm)
            #pragma unroll
            for (int ks = 0; ks < 2; ++ks) {
                const int r  = wr * 64 + fm * 16 + (lane & 15);
                const int sl = (ks * 4 + (lane >> 4)) ^ (r & 7);
                af[fm][ks] = *(const short8*)(lA + r * 64 + sl * 8);
            }
        #pragma unroll
        for (int fn = 0; fn < 4; ++fn)
            #pragma unroll
            for (int ks = 0; ks < 2; ++ks) {
                const int r  = wc * 64 + fn * 16 + (lane & 15);
                const int sl = (ks * 4 + (lane >> 4)) ^ (r & 7);
                bq[fn][ks] = *(const short8*)(lB + r * 64 + sl * 8);
            }
    };

    f32x4 accE[4][4] = {}, accO[4][4] = {};

    #define MMA2(ACC) {                                                        \
        __builtin_amdgcn_s_setprio(1);                                         \
        _Pragma("unroll") for (int ks = 0; ks < 2; ++ks)                       \
          _Pragma("unroll") for (int fm = 0; fm < 4; ++fm)                     \
            _Pragma("unroll") for (int fn = 0; fn < 4; ++fn)                   \
              ACC[fm][fn] = __builtin_amdgcn_mfma_f32_16x16x32_bf16(           \
                  af[fm][ks], bq[fn][ks], ACC[fm][fn], 0, 0, 0);               \
        __builtin_amdgcn_s_setprio(0); }

    stage(0, 0);
    stage(1, 1);
    VM6();
    BAR();

    for (int t = 0; t < 8; ++t) {                 // first half: accE (Re @ Mc^T)
        ldregs(t % 3);
        stage(t + 2, (t + 2) % 3);                // t+2 <= 9 < 16, always real
        VM6();
        LGKM0();
        BAR();
        MMA2(accE);
    }
    for (int t = 8; t < 16; ++t) {                // second half: accO (Im @ Ms^T)
        const int tp = (t + 2 < 16) ? t + 2 : 15;
        ldregs(t % 3);
        stage(tp, (t + 2) % 3);
        VM6();
        LGKM0();
        BAR();
        MMA2(accO);
    }
    VM0();
    BAR();
    #undef MMA2

    // two-pass epilogue: accE -> pe tile, accO -> po tile (stride 512)
    char* eb = (char*)lds;
    #define EPIPASS(ACC, DST) {                                                 \
        _Pragma("unroll") for (int fm = 0; fm < 4; ++fm)                        \
        _Pragma("unroll") for (int fn = 0; fn < 4; ++fn) {                      \
            const int col = wc * 64 + fn * 16 + (lane & 15);                    \
            _Pragma("unroll") for (int r = 0; r < 4; ++r) {                     \
                const int row = wr * 64 + fm * 16 + (lane >> 4) * 4 + r;        \
                const int sw = (col >> 3) ^ (((row >> 2) & 7) << 1);            \
                *(bf16*)(eb + row * 256 + sw * 16 + (col & 7) * 2) =            \
                    __float2bfloat16(ACC[fm][fn][r]);                           \
            }                                                                   \
        }                                                                       \
        asm volatile("s_waitcnt lgkmcnt(0)" ::: "memory");                      \
        BAR();                                                                  \
        _Pragma("unroll") for (int k2 = 0; k2 < 8; ++k2) {                      \
            const int g   = tid + k2 * 512;                                     \
            const int row = g >> 4;                                             \
            const int s   = g & 15;                                             \
            const int sw  = s ^ (((row >> 2) & 7) << 1);                        \
            short8 vv = *(const short8*)(eb + row * 256 + sw * 16);             \
            const int colg = col0 + s * 8;                                      \
            *(short8*)(DST + (size_t)(row0 + row) * 512 + colg) = vv;           \
        }                                                                       \
        BAR();                                                                  \
    }
    EPIPASS(accE, pe)
    EPIPASS(accO, po)
    #undef EPIPASS
}

// ------- overlap-add: frames[n] = (e[nbar] + (-1)^n R512/1024 -+ o[nbar]) * w[n]
__global__ void ola_k(const bf16* __restrict__ pe, const bf16* __restrict__ po,
                      const float* __restrict__ R512, const float* __restrict__ E512,
                      const float* __restrict__ wg, float* __restrict__ out) {
    __shared__ float w[1024], w2[1024];
    for (int i = threadIdx.x; i < 1024; i += 256) { w[i] = wg[i]; w2[i] = wg[1024 + i]; }
    __syncthreads();
    const int gid = blockIdx.x * 256 + threadIdx.x;
    const int o0  = gid * 8;
    const int bb  = o0 >> 19;
    const int oo  = o0 & 524287;
    const int s   = oo + 384;                     // multiple of 8
    const int tmax = s >> 8;
    float sum[8] = {}, env[8] = {};
    #pragma unroll
    for (int jj = 0; jj < 4; ++jj) {
        const int t = tmax - jj;
        if (t < 0 || t >= 2048) continue;
        const int n0 = s - (t << 8);              // [0,1016], multiple of 8
        const size_t rowi = (size_t)bb * 2048 + t;
        const size_t rb = rowi * 512;
        const float rc = R512[rowi] * (1.0f / 1024.0f);
        if (n0 <= 504) {                          // n = n0+e, parity = e&1
            short8 E  = *(const short8*)(pe + rb + n0);
            short8 Og = *(const short8*)(po + rb + n0);
            #pragma unroll
            for (int e = 0; e < 8; ++e) {
                float ev = b2f(E[e]) + ((e & 1) ? -rc : rc);
                sum[e] += (ev - b2f(Og[e])) * w[n0 + e];
                env[e] += w2[n0 + e];
            }
        } else {
            const int nb = 1024 - n0;             // [8,512], multiple of 8
            short8 Ea = *(const short8*)(pe + rb + nb - 8);
            short8 Oa = *(const short8*)(po + rb + nb - 8);
            float e0, o0v;
            if (nb < 512) {
                e0  = b2f(*(const short*)(pe + rb + nb));
                o0v = b2f(*(const short*)(po + rb + nb));
            } else {                              // nbar == 512
                e0  = E512[rowi];
                o0v = 0.0f;
            }
            sum[0] += (e0 + rc + o0v) * w[n0];
            env[0] += w2[n0];
            #pragma unroll
            for (int j = 1; j < 8; ++j) {
                float ev = b2f(Ea[8 - j]) + ((j & 1) ? -rc : rc);
                sum[j] += (ev + b2f(Oa[8 - j])) * w[n0 + j];
                env[j] += w2[n0 + j];
            }
        }
    }
    float4 r0, r1;
    r0.x = sum[0] / (env[0] + 1e-11f); r0.y = sum[1] / (env[1] + 1e-11f);
    r0.z = sum[2] / (env[2] + 1e-11f); r0.w = sum[3] / (env[3] + 1e-11f);
    r1.x = sum[4] / (env[4] + 1e-11f); r1.y = sum[5] / (env[5] + 1e-11f);
    r1.z = sum[6] / (env[6] + 1e-11f); r1.w = sum[7] / (env[7] + 1e-11f);
    *(float4*)(out + o0)     = r0;
    *(float4*)(out + o0 + 4) = r1;
}

// ---------------------------------------------------------------------- launcher
// ws budget ~137.5 MB, below the proven 140.6 MB bound.
extern "C" void kernel_launch(void* const* d_in, const int* in_sizes, int n_in,
                              void* d_out, int out_size, void* d_ws, size_t ws_size,
                              hipStream_t stream)
{
    const float* x = (const float*)d_in[0];
    const float* W = (const float*)d_in[1];
    const float* b = (const float*)d_in[2];
    float* out = (float*)d_out;

    char* ws = (char*)d_ws;
    size_t off = 0;
    auto alloc = [&](size_t bytes) { char* p = ws + off; off += (bytes + 255) & ~255ull; return p; };

    bf16*  Mc   = (bf16*) alloc(512ull * 512 * 2);     //    524,288
    bf16*  Ms   = (bf16*) alloc(512ull * 512 * 2);     //    524,288
    float* wg   = (float*)alloc(2048 * 4);             //      8,192
    float* br   = (float*)alloc(1152 * 4);             //      4,608
    float* Wcp  = (float*)alloc(1026 * 4);             //      4,104
    float* R512 = (float*)alloc(32768ull * 4);         //    131,072
    float* E512 = (float*)alloc(32768ull * 4);         //    131,072
    bf16*  Sri  = (bf16*) alloc(32768ull * 1032 * 2);  // 67,633,152
    char*  regC = alloc(68157440ull);                  // 68,157,440 (aliased)
    bf16*  xb = (bf16*)regC;                           // phase 1 (GEMM1 input)
    bf16*  Wr = (bf16*)(regC + 33554432ull);           // phase 1 [1024][512]
    bf16*  pe = (bf16*)regC;                           // phase 2 e [32768][512]
    bf16*  po = (bf16*)(regC + 33554432ull);           // phase 2 o [32768][512]

    hipFuncSetAttribute(reinterpret_cast<const void*>(gemm1_k),
                        hipFuncAttributeMaxDynamicSharedMemorySize, 73728);
    hipFuncSetAttribute(reinterpret_cast<const void*>(gemm2_k),
                        hipFuncAttributeMaxDynamicSharedMemorySize, 147456);

    prep_w_k  <<<dim3(1026),  dim3(256), 0, stream>>>(W, b, Wr, br, Wcp);
    cvt_x_k   <<<dim3(8192),  dim3(256), 0, stream>>>(x, xb, Wcp, R512);
    prep_mcs_k<<<dim3(512),   dim3(256), 0, stream>>>(Mc, Ms);
    prep_win_k<<<dim3(4),     dim3(256), 0, stream>>>(wg);
    // GEMM1: Sri = epi(xb @ Wr^T), tile-local [Re64|Im64], BK=32, 2 blocks/CU
    gemm1_k<<<dim3(1024), dim3(512), 73728, stream>>>(xb, Wr, br, Sri);
    // e[512] per row (alternating Re sum, f32)
    e512_k <<<dim3(8192), dim3(256), 0, stream>>>(Sri, E512);
    // GEMM2: accE/accO split-loop BK=64 pipeline, grid 512 = 2.0 rounds -> pe, po
    gemm2_k<<<dim3(512), dim3(512), 147456, stream>>>(Sri, Mc, Ms, pe, po);
    // OLA + fold combine + envelope normalize + trim
    ola_k  <<<dim3(4096), dim3(256), 0, stream>>>(pe, po, R512, E512, wg, out);
    (void)in_sizes; (void)n_in; (void)out_size; (void)ws_size;
}

// Round 22
// 165.546 us; speedup vs baseline: 1.0496x; 1.0003x over previous
//
#include <hip/hip_runtime.h>
#include <hip/hip_bf16.h>
#include <cstdint>
#include <cstddef>

typedef __hip_bfloat16 bf16;
using short8 = __attribute__((ext_vector_type(8))) short;
using f32x4  = __attribute__((ext_vector_type(4))) float;

static constexpr float kTwoPi = 6.283185307179586f;

#define GLDS(g, l) __builtin_amdgcn_global_load_lds(                       \
    (const __attribute__((address_space(1))) uint32_t*)(g),                \
    (__attribute__((address_space(3))) uint32_t*)(l), 16, 0, 0)

#define BAR()   { __builtin_amdgcn_sched_barrier(0); __builtin_amdgcn_s_barrier(); \
                  asm volatile("" ::: "memory"); }
#define LGKM0() { asm volatile("s_waitcnt lgkmcnt(0)" ::: "memory"); __builtin_amdgcn_sched_barrier(0); }
#define VM6()   { asm volatile("s_waitcnt vmcnt(6)"   ::: "memory"); __builtin_amdgcn_sched_barrier(0); }
#define VM3()   { asm volatile("s_waitcnt vmcnt(3)"   ::: "memory"); __builtin_amdgcn_sched_barrier(0); }
#define VM0()   { asm volatile("s_waitcnt vmcnt(0)"   ::: "memory"); __builtin_amdgcn_sched_barrier(0); }

static __device__ __forceinline__ float b2f(short u) {
    union { short s; bf16 h; } c; c.s = u; return __bfloat162float(c.h);
}

// -------------------- prep: W -> Wr [1024][512] + br + Wcp (Nyquist cols, f32)
__global__ void prep_w_k(const float* __restrict__ W, const float* __restrict__ b,
                         bf16* __restrict__ Wr, float* __restrict__ br,
                         float* __restrict__ Wcp) {
    int j = blockIdx.x;
    if (j < 1024) {
        int col = (j & 1) ? 513 + (j >> 1) : (j >> 1);
        for (int k = threadIdx.x; k < 512; k += 256)
            Wr[(size_t)j * 512 + k] = __float2bfloat16(W[(size_t)k * 1026 + col]);
        if (threadIdx.x == 0) br[j] = b[col];
    } else {
        int col = (j == 1024) ? 512 : 1025;
        for (int k = threadIdx.x; k < 512; k += 256)
            Wcp[(j - 1024) * 512 + k] = W[(size_t)k * 1026 + col];
        if (threadIdx.x == 0) Wcp[1024 + (j - 1024)] = b[col];
    }
}

// ------------------- prep: x -> bf16, fused Nyquist-bin dot (f32) -> R512[row]
__global__ void cvt_x_k(const float* __restrict__ x, bf16* __restrict__ xb,
                        const float* __restrict__ Wcp, float* __restrict__ R512) {
    const int tid = threadIdx.x, w = tid >> 6, lane = tid & 63;
    size_t i = ((size_t)blockIdx.x * 256 + tid) * 8;
    float4 a = *(const float4*)(x + i);
    float4 c = *(const float4*)(x + i + 4);
    union { bf16 h[8]; uint4 u; } o;
    o.h[0] = __float2bfloat16(a.x); o.h[1] = __float2bfloat16(a.y);
    o.h[2] = __float2bfloat16(a.z); o.h[3] = __float2bfloat16(a.w);
    o.h[4] = __float2bfloat16(c.x); o.h[5] = __float2bfloat16(c.y);
    o.h[6] = __float2bfloat16(c.z); o.h[7] = __float2bfloat16(c.w);
    *(uint4*)(xb + i) = o.u;
    const int kb = lane * 8;
    float4 m0 = *(const float4*)(Wcp + kb);
    float4 m1 = *(const float4*)(Wcp + kb + 4);
    float4 p0 = *(const float4*)(Wcp + 512 + kb);
    float4 p1 = *(const float4*)(Wcp + 512 + kb + 4);
    float dm = a.x*m0.x + a.y*m0.y + a.z*m0.z + a.w*m0.w
             + c.x*m1.x + c.y*m1.y + c.z*m1.z + c.w*m1.w;
    float dp = a.x*p0.x + a.y*p0.y + a.z*p0.z + a.w*p0.w
             + c.x*p1.x + c.y*p1.y + c.z*p1.z + c.w*p1.w;
    #pragma unroll
    for (int off = 32; off; off >>= 1) {
        dm += __shfl_xor(dm, off);
        dp += __shfl_xor(dp, off);
    }
    if (lane == 0) {
        float mag = fminf(__expf(dm + Wcp[1024]), 100.0f);
        R512[blockIdx.x * 4 + w] = mag * __cosf(dp + Wcp[1025]);
    }
}

// ------------------------- prep: Mc/Ms [512][512] cos/sin irfft half-matrices
__global__ void prep_mcs_k(bf16* __restrict__ Mc, bf16* __restrict__ Ms) {
    const int r = blockIdx.x;                     // output row n-bar (0..511)
    for (int kk = threadIdx.x; kk < 512; kk += 256) {
        int mm = (kk * r) & 1023;
        float ang = kTwoPi * (float)mm * (1.0f / 1024.0f);
        float alpha = (kk == 0) ? 1.0f : 2.0f;
        Mc[(size_t)r * 512 + kk] = __float2bfloat16(alpha * (1.0f / 1024.0f) * cosf(ang));
        Ms[(size_t)r * 512 + kk] = __float2bfloat16(alpha * (1.0f / 1024.0f) * sinf(ang));
    }
}

// ------------------------------------------------------- prep: window tables
__global__ void prep_win_k(float* __restrict__ wg) {
    const int idx = blockIdx.x * 256 + threadIdx.x;   // 0..1023
    float wn = 0.5f - 0.5f * cosf(kTwoPi * (float)idx / 1023.0f);  // numpy hanning
    wg[idx] = wn;
    wg[1024 + idx] = wn * wn;
}

// --------------------- GEMM1 (R19 body, measured 59.4us — best): 256x128, BK=32,
// 8 waves 4Mx2N, 3 slabs x 24KB = 72KB -> 2 blocks/CU (16 waves/CU latency hiding;
// R20's 4-wave fat-tile variant measured WORSE, 67us). Swizzle: slot^(row&3)^((row>>2)&3).
// Epilogue: Vocos + tile-local [Re_64 | Im_64] de-interleave.
__global__ __launch_bounds__(512, 4)
void gemm1_k(const bf16* __restrict__ A, const bf16* __restrict__ B,
             const float* __restrict__ bias, bf16* __restrict__ O)
{
    extern __shared__ __align__(16) bf16 lds[];   // 3 slabs x 12288 elems
    const int tid  = threadIdx.x;
    const int w    = tid >> 6;
    const int lane = tid & 63;
    const int wr = w >> 1, wc = w & 1;            // wave grid 4(M) x 2(N)

    const int nwg = gridDim.x, orig = blockIdx.x;
    const int bid = (orig & 7) * (nwg >> 3) + (orig >> 3);
    const int nt = bid & 7, mt = bid >> 3;
    const int row0 = mt * 256;
    const int col0 = nt * 128;

    const int q = lane >> 2;
    const int gslot = (lane & 3) ^ ((lane >> 2) & 3) ^ ((lane >> 4) & 3);

    const bf16* gA0 = A + (size_t)(row0 + q) * 512 + gslot * 8;
    const bf16* gB0 = B + (size_t)(col0 + q) * 512 + gslot * 8;

    auto stage = [&](int t, int s) {
        bf16* lA = lds + s * 12288;
        bf16* lB = lA + 8192;
        #pragma unroll
        for (int l = 0; l < 2; ++l) {
            const int c = w * 2 + l;              // A: 16 chunks of 16 rows
            GLDS(gA0 + (size_t)(16 * c) * 512 + (size_t)t * 32, lA + c * 512 + lane * 8);
        }
        GLDS(gB0 + (size_t)(16 * w) * 512 + (size_t)t * 32, lB + w * 512 + lane * 8);
    };

    short8 af[4], bq[4];
    auto ldregs = [&](int s) {
        const bf16* lA = lds + s * 12288;
        const bf16* lB = lA + 8192;
        const int sl = (lane >> 4) ^ (lane & 3) ^ ((lane >> 2) & 3);  // s ^ m(r)
        #pragma unroll
        for (int fm = 0; fm < 4; ++fm) {
            const int r = wr * 64 + fm * 16 + (lane & 15);
            af[fm] = *(const short8*)(lA + r * 32 + sl * 8);
        }
        #pragma unroll
        for (int fn = 0; fn < 4; ++fn) {
            const int r = wc * 64 + fn * 16 + (lane & 15);
            bq[fn] = *(const short8*)(lB + r * 32 + sl * 8);
        }
    };

    f32x4 acc[4][4] = {};

    stage(0, 0);
    stage(1, 1);
    VM3();
    BAR();

    for (int t = 0; t < 16; ++t) {
        const int tp = (t + 2 < 16) ? t + 2 : 15;
        ldregs(t % 3);
        stage(tp, (t + 2) % 3);
        VM3();                                    // retire stage(t+1)
        LGKM0();
        BAR();
        __builtin_amdgcn_s_setprio(1);
        #pragma unroll
        for (int fm = 0; fm < 4; ++fm)
            #pragma unroll
            for (int fn = 0; fn < 4; ++fn)
                acc[fm][fn] = __builtin_amdgcn_mfma_f32_16x16x32_bf16(
                    af[fm], bq[fn], acc[fm][fn], 0, 0, 0);
        __builtin_amdgcn_s_setprio(0);
    }
    VM0();
    BAR();                                        // LDS free for epilogue

    // epilogue: acc -> LDS (swizzled, tile-local deinterleave) -> coalesced store
    char* eb = (char*)lds;                        // [256 rows][256 B] = 64KB
    #pragma unroll
    for (int fm = 0; fm < 4; ++fm) {
        #pragma unroll
        for (int fn = 0; fn < 4; ++fn) {
            const int col = wc * 64 + fn * 16 + (lane & 15);     // 0..127 in tile
            const int n   = col0 + col;                          // < 1024 always
            #pragma unroll
            for (int r = 0; r < 4; ++r) {
                const int row = wr * 64 + fm * 16 + (lane >> 4) * 4 + r;
                float v = acc[fm][fn][r] + bias[n];
                float vo = __shfl_xor(v, 1);
                float res = (n & 1) ? fminf(__expf(vo), 100.0f) * __sinf(v)
                                    : fminf(__expf(v), 100.0f) * __cosf(vo);
                const int colp = (col >> 1) + ((col & 1) << 6);  // [Re_64 | Im_64]
                const int sw = (colp >> 3) ^ (((row >> 2) & 7) << 1);
                *(bf16*)(eb + row * 256 + sw * 16 + (colp & 7) * 2) =
                    __float2bfloat16(res);
            }
        }
    }
    asm volatile("s_waitcnt lgkmcnt(0)" ::: "memory");
    BAR();

    #pragma unroll
    for (int k2 = 0; k2 < 8; ++k2) {
        const int g   = tid + k2 * 512;           // 0..4095 16B-chunks
        const int row = g >> 4;
        const int s   = g & 15;
        const int sw  = s ^ (((row >> 2) & 7) << 1);
        short8 vv = *(const short8*)(eb + row * 256 + sw * 16);
        const int colg = col0 + s * 8;
        *(short8*)(O + (size_t)(row0 + row) * 1032 + colg) = vv;
    }
}

// ----------- e512_k: E512[row] = sum_k alpha_k (-1)^k Re_k / 1024 (f32, exact coefs)
__global__ void e512_k(const bf16* __restrict__ S, float* __restrict__ E512) {
    const int tid = threadIdx.x, w = tid >> 6, lane = tid & 63;
    const int row = blockIdx.x * 4 + w;
    const bf16* rp = S + (size_t)row * 1032;
    float acc = 0.0f;
    #pragma unroll
    for (int j = 0; j < 8; ++j) {
        float v = __bfloat162float(rp[j * 128 + lane]);
        float coef = (j == 0 && lane == 0) ? 1.0f : ((lane & 1) ? -2.0f : 2.0f);
        acc += v * coef;
    }
    #pragma unroll
    for (int off = 32; off; off >>= 1) acc += __shfl_xor(acc, off);
    if (lane == 0) E512[row] = acc * (1.0f / 1024.0f);
}

// ---------------- GEMM2: accE = Re@Mc^T (t=0..7), accO = Im@Ms^T (t=8..15), split
// loops, BK=64, 144KB LDS. Grid 512 = 128mt x 4nt = exactly 2.0 rounds.
__global__ __launch_bounds__(512, 1)
void gemm2_k(const bf16* __restrict__ S, const bf16* __restrict__ Mc,
             const bf16* __restrict__ Ms, bf16* __restrict__ pe,
             bf16* __restrict__ po)
{
    extern __shared__ __align__(16) bf16 lds[];
    const int tid  = threadIdx.x;
    const int w    = tid >> 6;
    const int lane = tid & 63;
    const int wr = w >> 1, wc = w & 1;

    const int nwg = gridDim.x, orig = blockIdx.x;
    const int bid = (orig & 7) * (nwg >> 3) + (orig >> 3);
    const int nt = bid & 3, mt = bid >> 2;
    const int row0 = mt * 256;
    const int col0 = nt * 128;

    const int srow  = lane >> 3;
    const int sslot = (lane & 7) ^ srow;

    const bf16* gA0 = S  + (size_t)(row0 + srow) * 1032 + sslot * 8;
    const bf16* gBc = Mc + (size_t)(col0 + srow) * 512 + sslot * 8;
    const bf16* gBs = Ms + (size_t)(col0 + srow) * 512 + sslot * 8;

    auto stage = [&](int t, int s) {
        bf16* lA = lds + s * 24576;
        bf16* lB = lA + 16384;
        const bf16* gB = (t < 8) ? gBc : gBs;
        const size_t aoff = (t < 8) ? (size_t)t * 128 : (size_t)(t - 8) * 128 + 64;
        const int tk = t & 7;
        #pragma unroll
        for (int l = 0; l < 4; ++l) {
            const int c = w * 4 + l;
            GLDS(gA0 + (size_t)(8 * c) * 1032 + aoff, lA + c * 512 + lane * 8);
        }
        #pragma unroll
        for (int l = 0; l < 2; ++l) {
            const int d = w * 2 + l;
            GLDS(gB + (size_t)(8 * d) * 512 + (size_t)tk * 64, lB + d * 512 + lane * 8);
        }
    };

    short8 af[4][2], bq[4][2];
    auto ldregs = [&](int s) {
        const bf16* lA = lds + s * 24576;
        const bf16* lB = lA + 16384;
        #pragma unroll
        for (int fm = 0; fm < 4; ++fm)
            #pragma unroll
            for (int ks = 0; ks < 2; ++ks) {
                const int r  = wr * 64 + fm * 16 + (lane & 15);
                const int sl = (ks * 4 + (lane >> 4)) ^ (r & 7);
                af[fm][ks] = *(const short8*)(lA + r * 64 + sl * 8);
            }
        #pragma unroll
        for (int fn = 0; fn < 4; ++fn)
            #pragma unroll
            for (int ks = 0; ks < 2; ++ks) {
                const int r  = wc * 64 + fn * 16 + (lane & 15);
                const int sl = (ks * 4 + (lane >> 4)) ^ (r & 7);
                bq[fn][ks] = *(const short8*)(lB + r * 64 + sl * 8);
            }
    };

    f32x4 accE[4][4] = {}, accO[4][4] = {};

    #define MMA2(ACC) {                                                        \
        __builtin_amdgcn_s_setprio(1);                                         \
        _Pragma("unroll") for (int ks = 0; ks < 2; ++ks)                       \
          _Pragma("unroll") for (int fm = 0; fm < 4; ++fm)                     \
            _Pragma("unroll") for (int fn = 0; fn < 4; ++fn)                   \
              ACC[fm][fn] = __builtin_amdgcn_mfma_f32_16x16x32_bf16(           \
                  af[fm][ks], bq[fn][ks], ACC[fm][fn], 0, 0, 0);               \
        __builtin_amdgcn_s_setprio(0); }

    stage(0, 0);
    stage(1, 1);
    VM6();
    BAR();

    for (int t = 0; t < 8; ++t) {                 // first half: accE (Re @ Mc^T)
        ldregs(t % 3);
        stage(t + 2, (t + 2) % 3);                // t+2 <= 9 < 16, always real
        VM6();
        LGKM0();
        BAR();
        MMA2(accE);
    }
    for (int t = 8; t < 16; ++t) {                // second half: accO (Im @ Ms^T)
        const int tp = (t + 2 < 16) ? t + 2 : 15;
        ldregs(t % 3);
        stage(tp, (t + 2) % 3);
        VM6();
        LGKM0();
        BAR();
        MMA2(accO);
    }
    VM0();
    BAR();
    #undef MMA2

    // two-pass epilogue: accE -> pe tile, accO -> po tile (stride 512)
    char* eb = (char*)lds;
    #define EPIPASS(ACC, DST) {                                                 \
        _Pragma("unroll") for (int fm = 0; fm < 4; ++fm)                        \
        _Pragma("unroll") for (int fn = 0; fn < 4; ++fn) {                      \
            const int col = wc * 64 + fn * 16 + (lane & 15);                    \
            _Pragma("unroll") for (int r = 0; r < 4; ++r) {                     \
                const int row = wr * 64 + fm * 16 + (lane >> 4) * 4 + r;        \
                const int sw = (col >> 3) ^ (((row >> 2) & 7) << 1);            \
                *(bf16*)(eb + row * 256 + sw * 16 + (col & 7) * 2) =            \
                    __float2bfloat16(ACC[fm][fn][r]);                           \
            }                                                                   \
        }                                                                       \
        asm volatile("s_waitcnt lgkmcnt(0)" ::: "memory");                      \
        BAR();                                                                  \
        _Pragma("unroll") for (int k2 = 0; k2 < 8; ++k2) {                      \
            const int g   = tid + k2 * 512;                                     \
            const int row = g >> 4;                                             \
            const int s   = g & 15;                                             \
            const int sw  = s ^ (((row >> 2) & 7) << 1);                        \
            short8 vv = *(const short8*)(eb + row * 256 + sw * 16);             \
            const int colg = col0 + s * 8;                                      \
            *(short8*)(DST + (size_t)(row0 + row) * 512 + colg) = vv;           \
        }                                                                       \
        BAR();                                                                  \
    }
    EPIPASS(accE, pe)
    EPIPASS(accO, po)
    #undef EPIPASS
}

// ------- overlap-add: frames[n] = (e[nbar] + (-1)^n R512/1024 -+ o[nbar]) * w[n]
__global__ void ola_k(const bf16* __restrict__ pe, const bf16* __restrict__ po,
                      const float* __restrict__ R512, const float* __restrict__ E512,
                      const float* __restrict__ wg, float* __restrict__ out) {
    __shared__ float w[1024], w2[1024];
    for (int i = threadIdx.x; i < 1024; i += 256) { w[i] = wg[i]; w2[i] = wg[1024 + i]; }
    __syncthreads();
    const int gid = blockIdx.x * 256 + threadIdx.x;
    const int o0  = gid * 8;
    const int bb  = o0 >> 19;
    const int oo  = o0 & 524287;
    const int s   = oo + 384;                     // multiple of 8
    const int tmax = s >> 8;
    float sum[8] = {}, env[8] = {};
    #pragma unroll
    for (int jj = 0; jj < 4; ++jj) {
        const int t = tmax - jj;
        if (t < 0 || t >= 2048) continue;
        const int n0 = s - (t << 8);              // [0,1016], multiple of 8
        const size_t rowi = (size_t)bb * 2048 + t;
        const size_t rb = rowi * 512;
        const float rc = R512[rowi] * (1.0f / 1024.0f);
        if (n0 <= 504) {                          // n = n0+e, parity = e&1
            short8 E  = *(const short8*)(pe + rb + n0);
            short8 Og = *(const short8*)(po + rb + n0);
            #pragma unroll
            for (int e = 0; e < 8; ++e) {
                float ev = b2f(E[e]) + ((e & 1) ? -rc : rc);
                sum[e] += (ev - b2f(Og[e])) * w[n0 + e];
                env[e] += w2[n0 + e];
            }
        } else {
            const int nb = 1024 - n0;             // [8,512], multiple of 8
            short8 Ea = *(const short8*)(pe + rb + nb - 8);
            short8 Oa = *(const short8*)(po + rb + nb - 8);
            float e0, o0v;
            if (nb < 512) {
                e0  = b2f(*(const short*)(pe + rb + nb));
                o0v = b2f(*(const short*)(po + rb + nb));
            } else {                              // nbar == 512
                e0  = E512[rowi];
                o0v = 0.0f;
            }
            sum[0] += (e0 + rc + o0v) * w[n0];
            env[0] += w2[n0];
            #pragma unroll
            for (int j = 1; j < 8; ++j) {
                float ev = b2f(Ea[8 - j]) + ((j & 1) ? -rc : rc);
                sum[j] += (ev + b2f(Oa[8 - j])) * w[n0 + j];
                env[j] += w2[n0 + j];
            }
        }
    }
    float4 r0, r1;
    r0.x = sum[0] / (env[0] + 1e-11f); r0.y = sum[1] / (env[1] + 1e-11f);
    r0.z = sum[2] / (env[2] + 1e-11f); r0.w = sum[3] / (env[3] + 1e-11f);
    r1.x = sum[4] / (env[4] + 1e-11f); r1.y = sum[5] / (env[5] + 1e-11f);
    r1.z = sum[6] / (env[6] + 1e-11f); r1.w = sum[7] / (env[7] + 1e-11f);
    *(float4*)(out + o0)     = r0;
    *(float4*)(out + o0 + 4) = r1;
}

// ---------------------------------------------------------------------- launcher
// ws budget ~137.5 MB, below the proven 140.6 MB bound.
extern "C" void kernel_launch(void* const* d_in, const int* in_sizes, int n_in,
                              void* d_out, int out_size, void* d_ws, size_t ws_size,
                              hipStream_t stream)
{
    const float* x = (const float*)d_in[0];
    const float* W = (const float*)d_in[1];
    const float* b = (const float*)d_in[2];
    float* out = (float*)d_out;

    char* ws = (char*)d_ws;
    size_t off = 0;
    auto alloc = [&](size_t bytes) { char* p = ws + off; off += (bytes + 255) & ~255ull; return p; };

    bf16*  Mc   = (bf16*) alloc(512ull * 512 * 2);     //    524,288
    bf16*  Ms   = (bf16*) alloc(512ull * 512 * 2);     //    524,288
    float* wg   = (float*)alloc(2048 * 4);             //      8,192
    float* br   = (float*)alloc(1152 * 4);             //      4,608
    float* Wcp  = (float*)alloc(1026 * 4);             //      4,104
    float* R512 = (float*)alloc(32768ull * 4);         //    131,072
    float* E512 = (float*)alloc(32768ull * 4);         //    131,072
    bf16*  Sri  = (bf16*) alloc(32768ull * 1032 * 2);  // 67,633,152
    char*  regC = alloc(68157440ull);                  // 68,157,440 (aliased)
    bf16*  xb = (bf16*)regC;                           // phase 1 (GEMM1 input)
    bf16*  Wr = (bf16*)(regC + 33554432ull);           // phase 1 [1024][512]
    bf16*  pe = (bf16*)regC;                           // phase 2 e [32768][512]
    bf16*  po = (bf16*)(regC + 33554432ull);           // phase 2 o [32768][512]

    hipFuncSetAttribute(reinterpret_cast<const void*>(gemm1_k),
                        hipFuncAttributeMaxDynamicSharedMemorySize, 73728);
    hipFuncSetAttribute(reinterpret_cast<const void*>(gemm2_k),
                        hipFuncAttributeMaxDynamicSharedMemorySize, 147456);

    prep_w_k  <<<dim3(1026),  dim3(256), 0, stream>>>(W, b, Wr, br, Wcp);
    cvt_x_k   <<<dim3(8192),  dim3(256), 0, stream>>>(x, xb, Wcp, R512);
    prep_mcs_k<<<dim3(512),   dim3(256), 0, stream>>>(Mc, Ms);
    prep_win_k<<<dim3(4),     dim3(256), 0, stream>>>(wg);
    // GEMM1: Sri = epi(xb @ Wr^T), tile-local [Re64|Im64], BK=32, 2 blocks/CU
    gemm1_k<<<dim3(1024), dim3(512), 73728, stream>>>(xb, Wr, br, Sri);
    // e[512] per row (alternating Re sum, f32)
    e512_k <<<dim3(8192), dim3(256), 0, stream>>>(Sri, E512);
    // GEMM2: accE/accO split-loop BK=64 pipeline, grid 512 = 2.0 rounds -> pe, po
    gemm2_k<<<dim3(512), dim3(512), 147456, stream>>>(Sri, Mc, Ms, pe, po);
    // OLA + fold combine + envelope normalize + trim
    ola_k  <<<dim3(4096), dim3(256), 0, stream>>>(pe, po, R512, E512, wg, out);
    (void)in_sizes; (void)n_in; (void)out_size; (void)ws_size;
}

// Round 23
// 155.528 us; speedup vs baseline: 1.1172x; 1.0644x over previous
//
#include <hip/hip_runtime.h>
#include <hip/hip_bf16.h>
#include <cstdint>
#include <cstddef>

typedef __hip_bfloat16 bf16;
using short8 = __attribute__((ext_vector_type(8))) short;
using f32x4  = __attribute__((ext_vector_type(4))) float;

static constexpr float kTwoPi = 6.283185307179586f;

#define GLDS(g, l) __builtin_amdgcn_global_load_lds(                       \
    (const __attribute__((address_space(1))) uint32_t*)(g),                \
    (__attribute__((address_space(3))) uint32_t*)(l), 16, 0, 0)

#define BAR()   { __builtin_amdgcn_sched_barrier(0); __builtin_amdgcn_s_barrier(); \
                  asm volatile("" ::: "memory"); }
#define LGKM0() { asm volatile("s_waitcnt lgkmcnt(0)" ::: "memory"); __builtin_amdgcn_sched_barrier(0); }
#define VM6()   { asm volatile("s_waitcnt vmcnt(6)"   ::: "memory"); __builtin_amdgcn_sched_barrier(0); }
#define VM3()   { asm volatile("s_waitcnt vmcnt(3)"   ::: "memory"); __builtin_amdgcn_sched_barrier(0); }
#define VM0()   { asm volatile("s_waitcnt vmcnt(0)"   ::: "memory"); __builtin_amdgcn_sched_barrier(0); }

static __device__ __forceinline__ float b2f(short u) {
    union { short s; bf16 h; } c; c.s = u; return __bfloat162float(c.h);
}

// -------------------- prep: W -> Wr [1024][512] + br + Wcp (Nyquist cols, f32)
__global__ void prep_w_k(const float* __restrict__ W, const float* __restrict__ b,
                         bf16* __restrict__ Wr, float* __restrict__ br,
                         float* __restrict__ Wcp) {
    int j = blockIdx.x;
    if (j < 1024) {
        int col = (j & 1) ? 513 + (j >> 1) : (j >> 1);
        for (int k = threadIdx.x; k < 512; k += 256)
            Wr[(size_t)j * 512 + k] = __float2bfloat16(W[(size_t)k * 1026 + col]);
        if (threadIdx.x == 0) br[j] = b[col];
    } else {
        int col = (j == 1024) ? 512 : 1025;
        for (int k = threadIdx.x; k < 512; k += 256)
            Wcp[(j - 1024) * 512 + k] = W[(size_t)k * 1026 + col];
        if (threadIdx.x == 0) Wcp[1024 + (j - 1024)] = b[col];
    }
}

// ------------------- prep: x -> bf16, fused Nyquist-bin dot (f32) -> R512[row]
__global__ void cvt_x_k(const float* __restrict__ x, bf16* __restrict__ xb,
                        const float* __restrict__ Wcp, float* __restrict__ R512) {
    const int tid = threadIdx.x, w = tid >> 6, lane = tid & 63;
    size_t i = ((size_t)blockIdx.x * 256 + tid) * 8;
    float4 a = *(const float4*)(x + i);
    float4 c = *(const float4*)(x + i + 4);
    union { bf16 h[8]; uint4 u; } o;
    o.h[0] = __float2bfloat16(a.x); o.h[1] = __float2bfloat16(a.y);
    o.h[2] = __float2bfloat16(a.z); o.h[3] = __float2bfloat16(a.w);
    o.h[4] = __float2bfloat16(c.x); o.h[5] = __float2bfloat16(c.y);
    o.h[6] = __float2bfloat16(c.z); o.h[7] = __float2bfloat16(c.w);
    *(uint4*)(xb + i) = o.u;
    const int kb = lane * 8;
    float4 m0 = *(const float4*)(Wcp + kb);
    float4 m1 = *(const float4*)(Wcp + kb + 4);
    float4 p0 = *(const float4*)(Wcp + 512 + kb);
    float4 p1 = *(const float4*)(Wcp + 512 + kb + 4);
    float dm = a.x*m0.x + a.y*m0.y + a.z*m0.z + a.w*m0.w
             + c.x*m1.x + c.y*m1.y + c.z*m1.z + c.w*m1.w;
    float dp = a.x*p0.x + a.y*p0.y + a.z*p0.z + a.w*p0.w
             + c.x*p1.x + c.y*p1.y + c.z*p1.z + c.w*p1.w;
    #pragma unroll
    for (int off = 32; off; off >>= 1) {
        dm += __shfl_xor(dm, off);
        dp += __shfl_xor(dp, off);
    }
    if (lane == 0) {
        float mag = fminf(__expf(dm + Wcp[1024]), 100.0f);
        R512[blockIdx.x * 4 + w] = mag * __cosf(dp + Wcp[1025]);
    }
}

// --------- prep: Mc/Ms [512][512] cos/sin irfft half-matrices + window tables
// grid 516: blocks 0..511 -> Mc/Ms row; 512..515 -> window tables.
__global__ void prep_mw_k(bf16* __restrict__ Mc, bf16* __restrict__ Ms,
                          float* __restrict__ wg) {
    if (blockIdx.x < 512) {
        const int r = blockIdx.x;                 // output row n-bar (0..511)
        for (int kk = threadIdx.x; kk < 512; kk += 256) {
            int mm = (kk * r) & 1023;
            float ang = kTwoPi * (float)mm * (1.0f / 1024.0f);
            float alpha = (kk == 0) ? 1.0f : 2.0f;
            Mc[(size_t)r * 512 + kk] = __float2bfloat16(alpha * (1.0f / 1024.0f) * cosf(ang));
            Ms[(size_t)r * 512 + kk] = __float2bfloat16(alpha * (1.0f / 1024.0f) * sinf(ang));
        }
    } else {
        const int idx = (blockIdx.x - 512) * 256 + threadIdx.x;   // 0..1023
        float wn = 0.5f - 0.5f * cosf(kTwoPi * (float)idx / 1023.0f);  // numpy hanning
        wg[idx] = wn;
        wg[1024 + idx] = wn * wn;
    }
}

// --------------------- GEMM1 (R19 body, 59.4us best): 256x128, BK=32, 8 waves 4Mx2N,
// 3 slabs x 24KB = 72KB -> 2 blocks/CU (R20's fat-tile variant measured worse).
// Epilogue: Vocos + tile-local [Re_64 | Im_64] de-interleave + FUSED E512 partials
// (alternating Re-sum per row, read back from eb — replaces the e512_k re-read pass).
__global__ __launch_bounds__(512, 4)
void gemm1_k(const bf16* __restrict__ A, const bf16* __restrict__ B,
             const float* __restrict__ bias, bf16* __restrict__ O,
             float* __restrict__ Ep)
{
    extern __shared__ __align__(16) bf16 lds[];   // 3 slabs x 12288 elems
    const int tid  = threadIdx.x;
    const int w    = tid >> 6;
    const int lane = tid & 63;
    const int wr = w >> 1, wc = w & 1;            // wave grid 4(M) x 2(N)

    const int nwg = gridDim.x, orig = blockIdx.x;
    const int bid = (orig & 7) * (nwg >> 3) + (orig >> 3);
    const int nt = bid & 7, mt = bid >> 3;
    const int row0 = mt * 256;
    const int col0 = nt * 128;

    const int q = lane >> 2;
    const int gslot = (lane & 3) ^ ((lane >> 2) & 3) ^ ((lane >> 4) & 3);

    const bf16* gA0 = A + (size_t)(row0 + q) * 512 + gslot * 8;
    const bf16* gB0 = B + (size_t)(col0 + q) * 512 + gslot * 8;

    auto stage = [&](int t, int s) {
        bf16* lA = lds + s * 12288;
        bf16* lB = lA + 8192;
        #pragma unroll
        for (int l = 0; l < 2; ++l) {
            const int c = w * 2 + l;              // A: 16 chunks of 16 rows
            GLDS(gA0 + (size_t)(16 * c) * 512 + (size_t)t * 32, lA + c * 512 + lane * 8);
        }
        GLDS(gB0 + (size_t)(16 * w) * 512 + (size_t)t * 32, lB + w * 512 + lane * 8);
    };

    short8 af[4], bq[4];
    auto ldregs = [&](int s) {
        const bf16* lA = lds + s * 12288;
        const bf16* lB = lA + 8192;
        const int sl = (lane >> 4) ^ (lane & 3) ^ ((lane >> 2) & 3);  // s ^ m(r)
        #pragma unroll
        for (int fm = 0; fm < 4; ++fm) {
            const int r = wr * 64 + fm * 16 + (lane & 15);
            af[fm] = *(const short8*)(lA + r * 32 + sl * 8);
        }
        #pragma unroll
        for (int fn = 0; fn < 4; ++fn) {
            const int r = wc * 64 + fn * 16 + (lane & 15);
            bq[fn] = *(const short8*)(lB + r * 32 + sl * 8);
        }
    };

    f32x4 acc[4][4] = {};

    stage(0, 0);
    stage(1, 1);
    VM3();
    BAR();

    for (int t = 0; t < 16; ++t) {
        const int tp = (t + 2 < 16) ? t + 2 : 15;
        ldregs(t % 3);
        stage(tp, (t + 2) % 3);
        VM3();                                    // retire stage(t+1)
        LGKM0();
        BAR();
        __builtin_amdgcn_s_setprio(1);
        #pragma unroll
        for (int fm = 0; fm < 4; ++fm)
            #pragma unroll
            for (int fn = 0; fn < 4; ++fn)
                acc[fm][fn] = __builtin_amdgcn_mfma_f32_16x16x32_bf16(
                    af[fm], bq[fn], acc[fm][fn], 0, 0, 0);
        __builtin_amdgcn_s_setprio(0);
    }
    VM0();
    BAR();                                        // LDS free for epilogue

    // epilogue: acc -> LDS (swizzled, tile-local deinterleave) -> coalesced store
    char* eb = (char*)lds;                        // [256 rows][256 B] = 64KB
    #pragma unroll
    for (int fm = 0; fm < 4; ++fm) {
        #pragma unroll
        for (int fn = 0; fn < 4; ++fn) {
            const int col = wc * 64 + fn * 16 + (lane & 15);     // 0..127 in tile
            const int n   = col0 + col;                          // < 1024 always
            #pragma unroll
            for (int r = 0; r < 4; ++r) {
                const int row = wr * 64 + fm * 16 + (lane >> 4) * 4 + r;
                float v = acc[fm][fn][r] + bias[n];
                float vo = __shfl_xor(v, 1);
                float res = (n & 1) ? fminf(__expf(vo), 100.0f) * __sinf(v)
                                    : fminf(__expf(v), 100.0f) * __cosf(vo);
                const int colp = (col >> 1) + ((col & 1) << 6);  // [Re_64 | Im_64]
                const int sw = (colp >> 3) ^ (((row >> 2) & 7) << 1);
                *(bf16*)(eb + row * 256 + sw * 16 + (colp & 7) * 2) =
                    __float2bfloat16(res);
            }
        }
    }
    asm volatile("s_waitcnt lgkmcnt(0)" ::: "memory");
    BAR();

    // fused E512 partial: per row, sum_k coef(k)*Re_k over this tile's 64 bins.
    // bin k = 64*nt + s*8 + e lives at eb slot s (swizzled), elem e. Parity = e&1.
    if (tid < 256) {
        const int row = tid;
        float ps = 0.0f;
        #pragma unroll
        for (int s2 = 0; s2 < 8; ++s2) {
            const int sw = s2 ^ (((row >> 2) & 7) << 1);
            short8 vv = *(const short8*)(eb + row * 256 + sw * 16);
            #pragma unroll
            for (int e = 0; e < 8; ++e) {
                float coef = (nt == 0 && s2 == 0 && e == 0) ? 1.0f
                            : ((e & 1) ? -2.0f : 2.0f);
                ps += b2f(vv[e]) * coef;
            }
        }
        Ep[(size_t)nt * 32768 + row0 + row] = ps;
    }

    #pragma unroll
    for (int k2 = 0; k2 < 8; ++k2) {
        const int g   = tid + k2 * 512;           // 0..4095 16B-chunks
        const int row = g >> 4;
        const int s   = g & 15;
        const int sw  = s ^ (((row >> 2) & 7) << 1);
        short8 vv = *(const short8*)(eb + row * 256 + sw * 16);
        const int colg = col0 + s * 8;
        *(short8*)(O + (size_t)(row0 + row) * 1032 + colg) = vv;
    }
}

// ---------------- GEMM2: accE = Re@Mc^T (t=0..7), accO = Im@Ms^T (t=8..15), split
// loops, BK=64, 144KB LDS. Grid 512 = 128mt x 4nt = exactly 2.0 rounds.
__global__ __launch_bounds__(512, 1)
void gemm2_k(const bf16* __restrict__ S, const bf16* __restrict__ Mc,
             const bf16* __restrict__ Ms, bf16* __restrict__ pe,
             bf16* __restrict__ po)
{
    extern __shared__ __align__(16) bf16 lds[];
    const int tid  = threadIdx.x;
    const int w    = tid >> 6;
    const int lane = tid & 63;
    const int wr = w >> 1, wc = w & 1;

    const int nwg = gridDim.x, orig = blockIdx.x;
    const int bid = (orig & 7) * (nwg >> 3) + (orig >> 3);
    const int nt = bid & 3, mt = bid >> 2;
    const int row0 = mt * 256;
    const int col0 = nt * 128;

    const int srow  = lane >> 3;
    const int sslot = (lane & 7) ^ srow;

    const bf16* gA0 = S  + (size_t)(row0 + srow) * 1032 + sslot * 8;
    const bf16* gBc = Mc + (size_t)(col0 + srow) * 512 + sslot * 8;
    const bf16* gBs = Ms + (size_t)(col0 + srow) * 512 + sslot * 8;

    auto stage = [&](int t, int s) {
        bf16* lA = lds + s * 24576;
        bf16* lB = lA + 16384;
        const bf16* gB = (t < 8) ? gBc : gBs;
        const size_t aoff = (t < 8) ? (size_t)t * 128 : (size_t)(t - 8) * 128 + 64;
        const int tk = t & 7;
        #pragma unroll
        for (int l = 0; l < 4; ++l) {
            const int c = w * 4 + l;
            GLDS(gA0 + (size_t)(8 * c) * 1032 + aoff, lA + c * 512 + lane * 8);
        }
        #pragma unroll
        for (int l = 0; l < 2; ++l) {
            const int d = w * 2 + l;
            GLDS(gB + (size_t)(8 * d) * 512 + (size_t)tk * 64, lB + d * 512 + lane * 8);
        }
    };

    short8 af[4][2], bq[4][2];
    auto ldregs = [&](int s) {
        const bf16* lA = lds + s * 24576;
        const bf16* lB = lA + 16384;
        #pragma unroll
        for (int fm = 0; fm < 4; ++fm)
            #pragma unroll
            for (int ks = 0; ks < 2; ++ks) {
                const int r  = wr * 64 + fm * 16 + (lane & 15);
                const int sl = (ks * 4 + (lane >> 4)) ^ (r & 7);
                af[fm][ks] = *(const short8*)(lA + r * 64 + sl * 8);
            }
        #pragma unroll
        for (int fn = 0; fn < 4; ++fn)
            #pragma unroll
            for (int ks = 0; ks < 2; ++ks) {
                const int r  = wc * 64 + fn * 16 + (lane & 15);
                const int sl = (ks * 4 + (lane >> 4)) ^ (r & 7);
                bq[fn][ks] = *(const short8*)(lB + r * 64 + sl * 8);
            }
    };

    f32x4 accE[4][4] = {}, accO[4][4] = {};

    #define MMA2(ACC) {                                                        \
        __builtin_amdgcn_s_setprio(1);                                         \
        _Pragma("unroll") for (int ks = 0; ks < 2; ++ks)                       \
          _Pragma("unroll") for (int fm = 0; fm < 4; ++fm)                     \
            _Pragma("unroll") for (int fn = 0; fn < 4; ++fn)                   \
              ACC[fm][fn] = __builtin_amdgcn_mfma_f32_16x16x32_bf16(           \
                  af[fm][ks], bq[fn][ks], ACC[fm][fn], 0, 0, 0);               \
        __builtin_amdgcn_s_setprio(0); }

    stage(0, 0);
    stage(1, 1);
    VM6();
    BAR();

    for (int t = 0; t < 8; ++t) {                 // first half: accE (Re @ Mc^T)
        ldregs(t % 3);
        stage(t + 2, (t + 2) % 3);                // t+2 <= 9 < 16, always real
        VM6();
        LGKM0();
        BAR();
        MMA2(accE);
    }
    for (int t = 8; t < 16; ++t) {                // second half: accO (Im @ Ms^T)
        const int tp = (t + 2 < 16) ? t + 2 : 15;
        ldregs(t % 3);
        stage(tp, (t + 2) % 3);
        VM6();
        LGKM0();
        BAR();
        MMA2(accO);
    }
    VM0();
    BAR();
    #undef MMA2

    // two-pass epilogue: accE -> pe tile, accO -> po tile (stride 512)
    char* eb = (char*)lds;
    #define EPIPASS(ACC, DST) {                                                 \
        _Pragma("unroll") for (int fm = 0; fm < 4; ++fm)                        \
        _Pragma("unroll") for (int fn = 0; fn < 4; ++fn) {                      \
            const int col = wc * 64 + fn * 16 + (lane & 15);                    \
            _Pragma("unroll") for (int r = 0; r < 4; ++r) {                     \
                const int row = wr * 64 + fm * 16 + (lane >> 4) * 4 + r;        \
                const int sw = (col >> 3) ^ (((row >> 2) & 7) << 1);            \
                *(bf16*)(eb + row * 256 + sw * 16 + (col & 7) * 2) =            \
                    __float2bfloat16(ACC[fm][fn][r]);                           \
            }                                                                   \
        }                                                                       \
        asm volatile("s_waitcnt lgkmcnt(0)" ::: "memory");                      \
        BAR();                                                                  \
        _Pragma("unroll") for (int k2 = 0; k2 < 8; ++k2) {                      \
            const int g   = tid + k2 * 512;                                     \
            const int row = g >> 4;                                             \
            const int s   = g & 15;                                             \
            const int sw  = s ^ (((row >> 2) & 7) << 1);                        \
            short8 vv = *(const short8*)(eb + row * 256 + sw * 16);             \
            const int colg = col0 + s * 8;                                      \
            *(short8*)(DST + (size_t)(row0 + row) * 512 + colg) = vv;           \
        }                                                                       \
        BAR();                                                                  \
    }
    EPIPASS(accE, pe)
    EPIPASS(accO, po)
    #undef EPIPASS
}

// ------- overlap-add: frames[n] = (e[nbar] + (-1)^n R512/1024 -+ o[nbar]) * w[n]
// pe/po stride 512 (nbar 0..511); nbar==512 from sum of 8 Ep partials (o[512]=0).
__global__ void ola_k(const bf16* __restrict__ pe, const bf16* __restrict__ po,
                      const float* __restrict__ R512, const float* __restrict__ Ep,
                      const float* __restrict__ wg, float* __restrict__ out) {
    __shared__ float w[1024], w2[1024];
    for (int i = threadIdx.x; i < 1024; i += 256) { w[i] = wg[i]; w2[i] = wg[1024 + i]; }
    __syncthreads();
    const int gid = blockIdx.x * 256 + threadIdx.x;
    const int o0  = gid * 8;
    const int bb  = o0 >> 19;
    const int oo  = o0 & 524287;
    const int s   = oo + 384;                     // multiple of 8
    const int tmax = s >> 8;
    float sum[8] = {}, env[8] = {};
    #pragma unroll
    for (int jj = 0; jj < 4; ++jj) {
        const int t = tmax - jj;
        if (t < 0 || t >= 2048) continue;
        const int n0 = s - (t << 8);              // [0,1016], multiple of 8
        const size_t rowi = (size_t)bb * 2048 + t;
        const size_t rb = rowi * 512;
        const float rc = R512[rowi] * (1.0f / 1024.0f);
        if (n0 <= 504) {                          // n = n0+e, parity = e&1
            short8 E  = *(const short8*)(pe + rb + n0);
            short8 Og = *(const short8*)(po + rb + n0);
            #pragma unroll
            for (int e = 0; e < 8; ++e) {
                float ev = b2f(E[e]) + ((e & 1) ? -rc : rc);
                sum[e] += (ev - b2f(Og[e])) * w[n0 + e];
                env[e] += w2[n0 + e];
            }
        } else {
            const int nb = 1024 - n0;             // [8,512], multiple of 8
            short8 Ea = *(const short8*)(pe + rb + nb - 8);
            short8 Oa = *(const short8*)(po + rb + nb - 8);
            float e0, o0v;
            if (nb < 512) {
                e0  = b2f(*(const short*)(pe + rb + nb));
                o0v = b2f(*(const short*)(po + rb + nb));
            } else {                              // nbar == 512
                float ps = 0.0f;
                #pragma unroll
                for (int q2 = 0; q2 < 8; ++q2) ps += Ep[(size_t)q2 * 32768 + rowi];
                e0  = ps * (1.0f / 1024.0f);
                o0v = 0.0f;
            }
            sum[0] += (e0 + rc + o0v) * w[n0];
            env[0] += w2[n0];
            #pragma unroll
            for (int j = 1; j < 8; ++j) {
                float ev = b2f(Ea[8 - j]) + ((j & 1) ? -rc : rc);
                sum[j] += (ev + b2f(Oa[8 - j])) * w[n0 + j];
                env[j] += w2[n0 + j];
            }
        }
    }
    float4 r0, r1;
    r0.x = sum[0] / (env[0] + 1e-11f); r0.y = sum[1] / (env[1] + 1e-11f);
    r0.z = sum[2] / (env[2] + 1e-11f); r0.w = sum[3] / (env[3] + 1e-11f);
    r1.x = sum[4] / (env[4] + 1e-11f); r1.y = sum[5] / (env[5] + 1e-11f);
    r1.z = sum[6] / (env[6] + 1e-11f); r1.w = sum[7] / (env[7] + 1e-11f);
    *(float4*)(out + o0)     = r0;
    *(float4*)(out + o0 + 4) = r1;
}

// ---------------------------------------------------------------------- launcher
// ws budget 138.04 MB, below the proven 140.6 MB bound.
extern "C" void kernel_launch(void* const* d_in, const int* in_sizes, int n_in,
                              void* d_out, int out_size, void* d_ws, size_t ws_size,
                              hipStream_t stream)
{
    const float* x = (const float*)d_in[0];
    const float* W = (const float*)d_in[1];
    const float* b = (const float*)d_in[2];
    float* out = (float*)d_out;

    char* ws = (char*)d_ws;
    size_t off = 0;
    auto alloc = [&](size_t bytes) { char* p = ws + off; off += (bytes + 255) & ~255ull; return p; };

    bf16*  Mc   = (bf16*) alloc(512ull * 512 * 2);     //    524,288
    bf16*  Ms   = (bf16*) alloc(512ull * 512 * 2);     //    524,288
    float* wg   = (float*)alloc(2048 * 4);             //      8,192
    float* br   = (float*)alloc(1152 * 4);             //      4,608
    float* Wcp  = (float*)alloc(1026 * 4);             //      4,104
    float* R512 = (float*)alloc(32768ull * 4);         //    131,072
    float* Ep   = (float*)alloc(8ull * 32768 * 4);     //  1,048,576
    bf16*  Sri  = (bf16*) alloc(32768ull * 1032 * 2);  // 67,633,152
    char*  regC = alloc(68157440ull);                  // 68,157,440 (aliased)
    bf16*  xb = (bf16*)regC;                           // phase 1 (GEMM1 input)
    bf16*  Wr = (bf16*)(regC + 33554432ull);           // phase 1 [1024][512]
    bf16*  pe = (bf16*)regC;                           // phase 2 e [32768][512]
    bf16*  po = (bf16*)(regC + 33554432ull);           // phase 2 o [32768][512]

    hipFuncSetAttribute(reinterpret_cast<const void*>(gemm1_k),
                        hipFuncAttributeMaxDynamicSharedMemorySize, 73728);
    hipFuncSetAttribute(reinterpret_cast<const void*>(gemm2_k),
                        hipFuncAttributeMaxDynamicSharedMemorySize, 147456);

    prep_w_k <<<dim3(1026), dim3(256), 0, stream>>>(W, b, Wr, br, Wcp);
    cvt_x_k  <<<dim3(8192), dim3(256), 0, stream>>>(x, xb, Wcp, R512);
    prep_mw_k<<<dim3(516),  dim3(256), 0, stream>>>(Mc, Ms, wg);
    // GEMM1: Sri = epi(xb @ Wr^T), tile-local [Re64|Im64], BK=32, 2 blocks/CU,
    // fused E512 partials -> Ep[8][32768]
    gemm1_k<<<dim3(1024), dim3(512), 73728, stream>>>(xb, Wr, br, Sri, Ep);
    // GEMM2: accE/accO split-loop BK=64 pipeline, grid 512 = 2.0 rounds -> pe, po
    gemm2_k<<<dim3(512), dim3(512), 147456, stream>>>(Sri, Mc, Ms, pe, po);
    // OLA + fold combine + envelope normalize + trim
    ola_k  <<<dim3(4096), dim3(256), 0, stream>>>(pe, po, R512, Ep, wg, out);
    (void)in_sizes; (void)n_in; (void)out_size; (void)ws_size;
}

// Round 24
// 152.754 us; speedup vs baseline: 1.1375x; 1.0182x over previous
//
#include <hip/hip_runtime.h>
#include <hip/hip_bf16.h>
#include <cstdint>
#include <cstddef>

typedef __hip_bfloat16 bf16;
using short8 = __attribute__((ext_vector_type(8))) short;
using f32x4  = __attribute__((ext_vector_type(4))) float;

static constexpr float kTwoPi = 6.283185307179586f;

#define GLDS(g, l) __builtin_amdgcn_global_load_lds(                       \
    (const __attribute__((address_space(1))) uint32_t*)(g),                \
    (__attribute__((address_space(3))) uint32_t*)(l), 16, 0, 0)

#define BAR()   { __builtin_amdgcn_sched_barrier(0); __builtin_amdgcn_s_barrier(); \
                  asm volatile("" ::: "memory"); }
#define LGKM0() { asm volatile("s_waitcnt lgkmcnt(0)" ::: "memory"); __builtin_amdgcn_sched_barrier(0); }
#define VM6()   { asm volatile("s_waitcnt vmcnt(6)"   ::: "memory"); __builtin_amdgcn_sched_barrier(0); }
#define VM3()   { asm volatile("s_waitcnt vmcnt(3)"   ::: "memory"); __builtin_amdgcn_sched_barrier(0); }
#define VM0()   { asm volatile("s_waitcnt vmcnt(0)"   ::: "memory"); __builtin_amdgcn_sched_barrier(0); }

static __device__ __forceinline__ float b2f(short u) {
    union { short s; bf16 h; } c; c.s = u; return __bfloat162float(c.h);
}

// --------- merged prep: W rearrange + Nyquist cols + Mc/Ms + window tables
// grid 1542: [0,1024) Wr rows; [1024,1026) Wcp; [1026,1538) Mc/Ms rows;
// [1538,1542) window tables. All outputs disjoint.
__global__ void prep_all_k(const float* __restrict__ W, const float* __restrict__ b,
                           bf16* __restrict__ Wr, float* __restrict__ br,
                           float* __restrict__ Wcp, bf16* __restrict__ Mc,
                           bf16* __restrict__ Ms, float* __restrict__ wg) {
    const int j = blockIdx.x;
    if (j < 1024) {
        int col = (j & 1) ? 513 + (j >> 1) : (j >> 1);
        for (int k = threadIdx.x; k < 512; k += 256)
            Wr[(size_t)j * 512 + k] = __float2bfloat16(W[(size_t)k * 1026 + col]);
        if (threadIdx.x == 0) br[j] = b[col];
    } else if (j < 1026) {
        int col = (j == 1024) ? 512 : 1025;
        for (int k = threadIdx.x; k < 512; k += 256)
            Wcp[(j - 1024) * 512 + k] = W[(size_t)k * 1026 + col];
        if (threadIdx.x == 0) Wcp[1024 + (j - 1024)] = b[col];
    } else if (j < 1538) {
        const int r = j - 1026;                   // output row n-bar (0..511)
        for (int kk = threadIdx.x; kk < 512; kk += 256) {
            int mm = (kk * r) & 1023;
            float ang = kTwoPi * (float)mm * (1.0f / 1024.0f);
            float alpha = (kk == 0) ? 1.0f : 2.0f;
            Mc[(size_t)r * 512 + kk] = __float2bfloat16(alpha * (1.0f / 1024.0f) * cosf(ang));
            Ms[(size_t)r * 512 + kk] = __float2bfloat16(alpha * (1.0f / 1024.0f) * sinf(ang));
        }
    } else {
        const int idx = (j - 1538) * 256 + threadIdx.x;   // 0..1023
        float wn = 0.5f - 0.5f * cosf(kTwoPi * (float)idx / 1023.0f);  // numpy hanning
        wg[idx] = wn;
        wg[1024 + idx] = wn * wn;
    }
}

// ------------------- prep: x -> bf16, fused Nyquist-bin dot (f32) -> R512[row]
__global__ void cvt_x_k(const float* __restrict__ x, bf16* __restrict__ xb,
                        const float* __restrict__ Wcp, float* __restrict__ R512) {
    const int tid = threadIdx.x, w = tid >> 6, lane = tid & 63;
    size_t i = ((size_t)blockIdx.x * 256 + tid) * 8;
    float4 a = *(const float4*)(x + i);
    float4 c = *(const float4*)(x + i + 4);
    union { bf16 h[8]; uint4 u; } o;
    o.h[0] = __float2bfloat16(a.x); o.h[1] = __float2bfloat16(a.y);
    o.h[2] = __float2bfloat16(a.z); o.h[3] = __float2bfloat16(a.w);
    o.h[4] = __float2bfloat16(c.x); o.h[5] = __float2bfloat16(c.y);
    o.h[6] = __float2bfloat16(c.z); o.h[7] = __float2bfloat16(c.w);
    *(uint4*)(xb + i) = o.u;
    const int kb = lane * 8;
    float4 m0 = *(const float4*)(Wcp + kb);
    float4 m1 = *(const float4*)(Wcp + kb + 4);
    float4 p0 = *(const float4*)(Wcp + 512 + kb);
    float4 p1 = *(const float4*)(Wcp + 512 + kb + 4);
    float dm = a.x*m0.x + a.y*m0.y + a.z*m0.z + a.w*m0.w
             + c.x*m1.x + c.y*m1.y + c.z*m1.z + c.w*m1.w;
    float dp = a.x*p0.x + a.y*p0.y + a.z*p0.z + a.w*p0.w
             + c.x*p1.x + c.y*p1.y + c.z*p1.z + c.w*p1.w;
    #pragma unroll
    for (int off = 32; off; off >>= 1) {
        dm += __shfl_xor(dm, off);
        dp += __shfl_xor(dp, off);
    }
    if (lane == 0) {
        float mag = fminf(__expf(dm + Wcp[1024]), 100.0f);
        R512[blockIdx.x * 4 + w] = mag * __cosf(dp + Wcp[1025]);
    }
}

// --------------------- GEMM1 (R19 body, 59.4us best): 256x128, BK=32, 8 waves 4Mx2N,
// 3 slabs x 24KB = 72KB -> 2 blocks/CU. Epilogue: Vocos + tile-local [Re64|Im64]
// de-interleave + fused E512 partials.
__global__ __launch_bounds__(512, 4)
void gemm1_k(const bf16* __restrict__ A, const bf16* __restrict__ B,
             const float* __restrict__ bias, bf16* __restrict__ O,
             float* __restrict__ Ep)
{
    extern __shared__ __align__(16) bf16 lds[];   // 3 slabs x 12288 elems
    const int tid  = threadIdx.x;
    const int w    = tid >> 6;
    const int lane = tid & 63;
    const int wr = w >> 1, wc = w & 1;            // wave grid 4(M) x 2(N)

    const int nwg = gridDim.x, orig = blockIdx.x;
    const int bid = (orig & 7) * (nwg >> 3) + (orig >> 3);
    const int nt = bid & 7, mt = bid >> 3;
    const int row0 = mt * 256;
    const int col0 = nt * 128;

    const int q = lane >> 2;
    const int gslot = (lane & 3) ^ ((lane >> 2) & 3) ^ ((lane >> 4) & 3);

    const bf16* gA0 = A + (size_t)(row0 + q) * 512 + gslot * 8;
    const bf16* gB0 = B + (size_t)(col0 + q) * 512 + gslot * 8;

    auto stage = [&](int t, int s) {
        bf16* lA = lds + s * 12288;
        bf16* lB = lA + 8192;
        #pragma unroll
        for (int l = 0; l < 2; ++l) {
            const int c = w * 2 + l;              // A: 16 chunks of 16 rows
            GLDS(gA0 + (size_t)(16 * c) * 512 + (size_t)t * 32, lA + c * 512 + lane * 8);
        }
        GLDS(gB0 + (size_t)(16 * w) * 512 + (size_t)t * 32, lB + w * 512 + lane * 8);
    };

    short8 af[4], bq[4];
    auto ldregs = [&](int s) {
        const bf16* lA = lds + s * 12288;
        const bf16* lB = lA + 8192;
        const int sl = (lane >> 4) ^ (lane & 3) ^ ((lane >> 2) & 3);  // s ^ m(r)
        #pragma unroll
        for (int fm = 0; fm < 4; ++fm) {
            const int r = wr * 64 + fm * 16 + (lane & 15);
            af[fm] = *(const short8*)(lA + r * 32 + sl * 8);
        }
        #pragma unroll
        for (int fn = 0; fn < 4; ++fn) {
            const int r = wc * 64 + fn * 16 + (lane & 15);
            bq[fn] = *(const short8*)(lB + r * 32 + sl * 8);
        }
    };

    f32x4 acc[4][4] = {};

    stage(0, 0);
    stage(1, 1);
    VM3();
    BAR();

    for (int t = 0; t < 16; ++t) {
        const int tp = (t + 2 < 16) ? t + 2 : 15;
        ldregs(t % 3);
        stage(tp, (t + 2) % 3);
        VM3();                                    // retire stage(t+1)
        LGKM0();
        BAR();
        __builtin_amdgcn_s_setprio(1);
        #pragma unroll
        for (int fm = 0; fm < 4; ++fm)
            #pragma unroll
            for (int fn = 0; fn < 4; ++fn)
                acc[fm][fn] = __builtin_amdgcn_mfma_f32_16x16x32_bf16(
                    af[fm], bq[fn], acc[fm][fn], 0, 0, 0);
        __builtin_amdgcn_s_setprio(0);
    }
    VM0();
    BAR();                                        // LDS free for epilogue

    // epilogue: acc -> LDS (swizzled, tile-local deinterleave) -> coalesced store
    char* eb = (char*)lds;                        // [256 rows][256 B] = 64KB
    #pragma unroll
    for (int fm = 0; fm < 4; ++fm) {
        #pragma unroll
        for (int fn = 0; fn < 4; ++fn) {
            const int col = wc * 64 + fn * 16 + (lane & 15);     // 0..127 in tile
            const int n   = col0 + col;                          // < 1024 always
            #pragma unroll
            for (int r = 0; r < 4; ++r) {
                const int row = wr * 64 + fm * 16 + (lane >> 4) * 4 + r;
                float v = acc[fm][fn][r] + bias[n];
                float vo = __shfl_xor(v, 1);
                float res = (n & 1) ? fminf(__expf(vo), 100.0f) * __sinf(v)
                                    : fminf(__expf(v), 100.0f) * __cosf(vo);
                const int colp = (col >> 1) + ((col & 1) << 6);  // [Re_64 | Im_64]
                const int sw = (colp >> 3) ^ (((row >> 2) & 7) << 1);
                *(bf16*)(eb + row * 256 + sw * 16 + (colp & 7) * 2) =
                    __float2bfloat16(res);
            }
        }
    }
    asm volatile("s_waitcnt lgkmcnt(0)" ::: "memory");
    BAR();

    // fused E512 partial: per row, sum_k coef(k)*Re_k over this tile's 64 bins.
    if (tid < 256) {
        const int row = tid;
        float ps = 0.0f;
        #pragma unroll
        for (int s2 = 0; s2 < 8; ++s2) {
            const int sw = s2 ^ (((row >> 2) & 7) << 1);
            short8 vv = *(const short8*)(eb + row * 256 + sw * 16);
            #pragma unroll
            for (int e = 0; e < 8; ++e) {
                float coef = (nt == 0 && s2 == 0 && e == 0) ? 1.0f
                            : ((e & 1) ? -2.0f : 2.0f);
                ps += b2f(vv[e]) * coef;
            }
        }
        Ep[(size_t)nt * 32768 + row0 + row] = ps;
    }

    #pragma unroll
    for (int k2 = 0; k2 < 8; ++k2) {
        const int g   = tid + k2 * 512;           // 0..4095 16B-chunks
        const int row = g >> 4;
        const int s   = g & 15;
        const int sw  = s ^ (((row >> 2) & 7) << 1);
        short8 vv = *(const short8*)(eb + row * 256 + sw * 16);
        const int colg = col0 + s * 8;
        *(short8*)(O + (size_t)(row0 + row) * 1032 + colg) = vv;
    }
}

// ---------------- GEMM2: accE = Re@Mc^T (t=0..7), accO = Im@Ms^T (t=8..15), split
// loops, BK=64, 144KB LDS. Grid 512 = 128mt x 4nt = exactly 2.0 rounds.
__global__ __launch_bounds__(512, 1)
void gemm2_k(const bf16* __restrict__ S, const bf16* __restrict__ Mc,
             const bf16* __restrict__ Ms, bf16* __restrict__ pe,
             bf16* __restrict__ po)
{
    extern __shared__ __align__(16) bf16 lds[];
    const int tid  = threadIdx.x;
    const int w    = tid >> 6;
    const int lane = tid & 63;
    const int wr = w >> 1, wc = w & 1;

    const int nwg = gridDim.x, orig = blockIdx.x;
    const int bid = (orig & 7) * (nwg >> 3) + (orig >> 3);
    const int nt = bid & 3, mt = bid >> 2;
    const int row0 = mt * 256;
    const int col0 = nt * 128;

    const int srow  = lane >> 3;
    const int sslot = (lane & 7) ^ srow;

    const bf16* gA0 = S  + (size_t)(row0 + srow) * 1032 + sslot * 8;
    const bf16* gBc = Mc + (size_t)(col0 + srow) * 512 + sslot * 8;
    const bf16* gBs = Ms + (size_t)(col0 + srow) * 512 + sslot * 8;

    auto stage = [&](int t, int s) {
        bf16* lA = lds + s * 24576;
        bf16* lB = lA + 16384;
        const bf16* gB = (t < 8) ? gBc : gBs;
        const size_t aoff = (t < 8) ? (size_t)t * 128 : (size_t)(t - 8) * 128 + 64;
        const int tk = t & 7;
        #pragma unroll
        for (int l = 0; l < 4; ++l) {
            const int c = w * 4 + l;
            GLDS(gA0 + (size_t)(8 * c) * 1032 + aoff, lA + c * 512 + lane * 8);
        }
        #pragma unroll
        for (int l = 0; l < 2; ++l) {
            const int d = w * 2 + l;
            GLDS(gB + (size_t)(8 * d) * 512 + (size_t)tk * 64, lB + d * 512 + lane * 8);
        }
    };

    short8 af[4][2], bq[4][2];
    auto ldregs = [&](int s) {
        const bf16* lA = lds + s * 24576;
        const bf16* lB = lA + 16384;
        #pragma unroll
        for (int fm = 0; fm < 4; ++fm)
            #pragma unroll
            for (int ks = 0; ks < 2; ++ks) {
                const int r  = wr * 64 + fm * 16 + (lane & 15);
                const int sl = (ks * 4 + (lane >> 4)) ^ (r & 7);
                af[fm][ks] = *(const short8*)(lA + r * 64 + sl * 8);
            }
        #pragma unroll
        for (int fn = 0; fn < 4; ++fn)
            #pragma unroll
            for (int ks = 0; ks < 2; ++ks) {
                const int r  = wc * 64 + fn * 16 + (lane & 15);
                const int sl = (ks * 4 + (lane >> 4)) ^ (r & 7);
                bq[fn][ks] = *(const short8*)(lB + r * 64 + sl * 8);
            }
    };

    f32x4 accE[4][4] = {}, accO[4][4] = {};

    #define MMA2(ACC) {                                                        \
        __builtin_amdgcn_s_setprio(1);                                         \
        _Pragma("unroll") for (int ks = 0; ks < 2; ++ks)                       \
          _Pragma("unroll") for (int fm = 0; fm < 4; ++fm)                     \
            _Pragma("unroll") for (int fn = 0; fn < 4; ++fn)                   \
              ACC[fm][fn] = __builtin_amdgcn_mfma_f32_16x16x32_bf16(           \
                  af[fm][ks], bq[fn][ks], ACC[fm][fn], 0, 0, 0);               \
        __builtin_amdgcn_s_setprio(0); }

    stage(0, 0);
    stage(1, 1);
    VM6();
    BAR();

    for (int t = 0; t < 8; ++t) {                 // first half: accE (Re @ Mc^T)
        ldregs(t % 3);
        stage(t + 2, (t + 2) % 3);                // t+2 <= 9 < 16, always real
        VM6();
        LGKM0();
        BAR();
        MMA2(accE);
    }
    for (int t = 8; t < 16; ++t) {                // second half: accO (Im @ Ms^T)
        const int tp = (t + 2 < 16) ? t + 2 : 15;
        ldregs(t % 3);
        stage(tp, (t + 2) % 3);
        VM6();
        LGKM0();
        BAR();
        MMA2(accO);
    }
    VM0();
    BAR();
    #undef MMA2

    // two-pass epilogue: accE -> pe tile, accO -> po tile (stride 512)
    char* eb = (char*)lds;
    #define EPIPASS(ACC, DST) {                                                 \
        _Pragma("unroll") for (int fm = 0; fm < 4; ++fm)                        \
        _Pragma("unroll") for (int fn = 0; fn < 4; ++fn) {                      \
            const int col = wc * 64 + fn * 16 + (lane & 15);                    \
            _Pragma("unroll") for (int r = 0; r < 4; ++r) {                     \
                const int row = wr * 64 + fm * 16 + (lane >> 4) * 4 + r;        \
                const int sw = (col >> 3) ^ (((row >> 2) & 7) << 1);            \
                *(bf16*)(eb + row * 256 + sw * 16 + (col & 7) * 2) =            \
                    __float2bfloat16(ACC[fm][fn][r]);                           \
            }                                                                   \
        }                                                                       \
        asm volatile("s_waitcnt lgkmcnt(0)" ::: "memory");                      \
        BAR();                                                                  \
        _Pragma("unroll") for (int k2 = 0; k2 < 8; ++k2) {                      \
            const int g   = tid + k2 * 512;                                     \
            const int row = g >> 4;                                             \
            const int s   = g & 15;                                             \
            const int sw  = s ^ (((row >> 2) & 7) << 1);                        \
            short8 vv = *(const short8*)(eb + row * 256 + sw * 16);             \
            const int colg = col0 + s * 8;                                      \
            *(short8*)(DST + (size_t)(row0 + row) * 512 + colg) = vv;           \
        }                                                                       \
        BAR();                                                                  \
    }
    EPIPASS(accE, pe)
    EPIPASS(accO, po)
    #undef EPIPASS
}

// ------- overlap-add: frames[n] = (e[nbar] + (-1)^n R512/1024 -+ o[nbar]) * w[n]
__global__ void ola_k(const bf16* __restrict__ pe, const bf16* __restrict__ po,
                      const float* __restrict__ R512, const float* __restrict__ Ep,
                      const float* __restrict__ wg, float* __restrict__ out) {
    __shared__ float w[1024], w2[1024];
    for (int i = threadIdx.x; i < 1024; i += 256) { w[i] = wg[i]; w2[i] = wg[1024 + i]; }
    __syncthreads();
    const int gid = blockIdx.x * 256 + threadIdx.x;
    const int o0  = gid * 8;
    const int bb  = o0 >> 19;
    const int oo  = o0 & 524287;
    const int s   = oo + 384;                     // multiple of 8
    const int tmax = s >> 8;
    float sum[8] = {}, env[8] = {};
    #pragma unroll
    for (int jj = 0; jj < 4; ++jj) {
        const int t = tmax - jj;
        if (t < 0 || t >= 2048) continue;
        const int n0 = s - (t << 8);              // [0,1016], multiple of 8
        const size_t rowi = (size_t)bb * 2048 + t;
        const size_t rb = rowi * 512;
        const float rc = R512[rowi] * (1.0f / 1024.0f);
        if (n0 <= 504) {                          // n = n0+e, parity = e&1
            short8 E  = *(const short8*)(pe + rb + n0);
            short8 Og = *(const short8*)(po + rb + n0);
            #pragma unroll
            for (int e = 0; e < 8; ++e) {
                float ev = b2f(E[e]) + ((e & 1) ? -rc : rc);
                sum[e] += (ev - b2f(Og[e])) * w[n0 + e];
                env[e] += w2[n0 + e];
            }
        } else {
            const int nb = 1024 - n0;             // [8,512], multiple of 8
            short8 Ea = *(const short8*)(pe + rb + nb - 8);
            short8 Oa = *(const short8*)(po + rb + nb - 8);
            float e0, o0v;
            if (nb < 512) {
                e0  = b2f(*(const short*)(pe + rb + nb));
                o0v = b2f(*(const short*)(po + rb + nb));
            } else {                              // nbar == 512
                float ps = 0.0f;
                #pragma unroll
                for (int q2 = 0; q2 < 8; ++q2) ps += Ep[(size_t)q2 * 32768 + rowi];
                e0  = ps * (1.0f / 1024.0f);
                o0v = 0.0f;
            }
            sum[0] += (e0 + rc + o0v) * w[n0];
            env[0] += w2[n0];
            #pragma unroll
            for (int j = 1; j < 8; ++j) {
                float ev = b2f(Ea[8 - j]) + ((j & 1) ? -rc : rc);
                sum[j] += (ev + b2f(Oa[8 - j])) * w[n0 + j];
                env[j] += w2[n0 + j];
            }
        }
    }
    float4 r0, r1;
    r0.x = sum[0] / (env[0] + 1e-11f); r0.y = sum[1] / (env[1] + 1e-11f);
    r0.z = sum[2] / (env[2] + 1e-11f); r0.w = sum[3] / (env[3] + 1e-11f);
    r1.x = sum[4] / (env[4] + 1e-11f); r1.y = sum[5] / (env[5] + 1e-11f);
    r1.z = sum[6] / (env[6] + 1e-11f); r1.w = sum[7] / (env[7] + 1e-11f);
    *(float4*)(out + o0)     = r0;
    *(float4*)(out + o0 + 4) = r1;
}

// ---------------------------------------------------------------------- launcher
// ws budget 138.04 MB, below the proven 140.6 MB bound.
extern "C" void kernel_launch(void* const* d_in, const int* in_sizes, int n_in,
                              void* d_out, int out_size, void* d_ws, size_t ws_size,
                              hipStream_t stream)
{
    const float* x = (const float*)d_in[0];
    const float* W = (const float*)d_in[1];
    const float* b = (const float*)d_in[2];
    float* out = (float*)d_out;

    char* ws = (char*)d_ws;
    size_t off = 0;
    auto alloc = [&](size_t bytes) { char* p = ws + off; off += (bytes + 255) & ~255ull; return p; };

    bf16*  Mc   = (bf16*) alloc(512ull * 512 * 2);     //    524,288
    bf16*  Ms   = (bf16*) alloc(512ull * 512 * 2);     //    524,288
    float* wg   = (float*)alloc(2048 * 4);             //      8,192
    float* br   = (float*)alloc(1152 * 4);             //      4,608
    float* Wcp  = (float*)alloc(1026 * 4);             //      4,104
    float* R512 = (float*)alloc(32768ull * 4);         //    131,072
    float* Ep   = (float*)alloc(8ull * 32768 * 4);     //  1,048,576
    bf16*  Sri  = (bf16*) alloc(32768ull * 1032 * 2);  // 67,633,152
    char*  regC = alloc(68157440ull);                  // 68,157,440 (aliased)
    bf16*  xb = (bf16*)regC;                           // phase 1 (GEMM1 input)
    bf16*  Wr = (bf16*)(regC + 33554432ull);           // phase 1 [1024][512]
    bf16*  pe = (bf16*)regC;                           // phase 2 e [32768][512]
    bf16*  po = (bf16*)(regC + 33554432ull);           // phase 2 o [32768][512]

    hipFuncSetAttribute(reinterpret_cast<const void*>(gemm1_k),
                        hipFuncAttributeMaxDynamicSharedMemorySize, 73728);
    hipFuncSetAttribute(reinterpret_cast<const void*>(gemm2_k),
                        hipFuncAttributeMaxDynamicSharedMemorySize, 147456);

    prep_all_k<<<dim3(1542), dim3(256), 0, stream>>>(W, b, Wr, br, Wcp, Mc, Ms, wg);
    cvt_x_k   <<<dim3(8192), dim3(256), 0, stream>>>(x, xb, Wcp, R512);
    // GEMM1: Sri = epi(xb @ Wr^T), tile-local [Re64|Im64], BK=32, 2 blocks/CU,
    // fused E512 partials -> Ep[8][32768]
    gemm1_k<<<dim3(1024), dim3(512), 73728, stream>>>(xb, Wr, br, Sri, Ep);
    // GEMM2: accE/accO split-loop BK=64 pipeline, grid 512 = 2.0 rounds -> pe, po
    gemm2_k<<<dim3(512), dim3(512), 147456, stream>>>(Sri, Mc, Ms, pe, po);
    // OLA + fold combine + envelope normalize + trim
    ola_k  <<<dim3(4096), dim3(256), 0, stream>>>(pe, po, R512, Ep, wg, out);
    (void)in_sizes; (void)n_in; (void)out_size; (void)ws_size;
}